// Round 2
// baseline (673.329 us; speedup 1.0000x reference)
//
#include <hip/hip_runtime.h>

// GAT 2-layer fused pipeline for MI355X.
// N=50000 nodes, E=800000 edges, H=4 heads, C=64 channels, D=4 att dims.
// Float inputs/outputs: dtype (fp32 vs packed bf16) detected at runtime by k_detect
// (low-u16 bf16-exponent-plausibility test); edge_index int32. Internal math fp32.
//
// Structure per call:
//   k_detect -> k_params (weights -> fp32 in ws)
//   CSR build (hist -> scan -> scatter), shared by both layers
//   layer: k_node (h = x@W, alpha_s/alpha_d from x@A)  ->  k_aggr (edge softmax
//          + weighted gather-sum per dst, head-mean, bias, leaky)
// Softmax max-subtraction skipped: alphas are O(0.1), exp() safe, softmax is
// shift-invariant -> matches reference to fp32 rounding.

#define N_NODES 50000
#define N_EDGES 800000

__device__ __forceinline__ float bf2f(unsigned short u){
  return __uint_as_float(((unsigned int)u) << 16);
}
__device__ __forceinline__ unsigned short f2bf(float f){
  unsigned int u = __float_as_uint(f);
  u = (u + 0x7FFFu + ((u >> 16) & 1u)) >> 16;   // round-to-nearest-even
  return (unsigned short)u;
}

// ---------------- dtype probe ----------------
// fp32 buffer: low u16 of each word = mantissa bits -> bf16-exponent ~uniform (hit ~14%).
// bf16 buffer: low u16 = an actual bf16 of N(0,1)-scale data -> exponent in [100,135] (~100%).
__global__ void k_detect(const unsigned int* __restrict__ xb, int* __restrict__ flag){
  int l = threadIdx.x;
  unsigned int w = xb[l] & 0xFFFFu;
  unsigned int e = (w >> 7) & 0xFFu;
  bool hit = (e >= 100u && e <= 135u);
  unsigned long long m = __ballot(hit);
  if (l == 0) *flag = (__popcll(m) > 40) ? 1 : 0;   // 1 = bf16 inputs
}

// ---------------- param conversion: all weights -> fp32 in ws ----------------
struct ParamPtrs { const void* src[10]; float* dst[10]; int len[10]; };

__global__ __launch_bounds__(256) void k_params(ParamPtrs P, const int* __restrict__ flag){
  const bool bf = (*flag != 0);
  const int a = blockIdx.y;
  const int i = blockIdx.x * 256 + threadIdx.x;
  if (i < P.len[a]){
    float v = bf ? bf2f(((const unsigned short*)P.src[a])[i]) : ((const float*)P.src[a])[i];
    P.dst[a][i] = v;
  }
}

// ---------------- CSR build ----------------

__global__ __launch_bounds__(256) void k_hist(const int* __restrict__ dst,
                                              int* __restrict__ deg){
  int e = blockIdx.x * 256 + threadIdx.x;
  if (e < N_EDGES) atomicAdd(&deg[dst[e]], 1);
}

__global__ __launch_bounds__(1024) void k_scan(const int* __restrict__ deg,
                                               int* __restrict__ rowptr){
  __shared__ int sm[1024];
  const int tid = threadIdx.x;
  int carry = 0;
  for (int base = 0; base < N_NODES; base += 1024){
    int v = (base + tid < N_NODES) ? deg[base + tid] : 0;
    sm[tid] = v;
    __syncthreads();
    for (int off = 1; off < 1024; off <<= 1){      // Hillis-Steele inclusive scan
      int t = (tid >= off) ? sm[tid - off] : 0;
      __syncthreads();
      sm[tid] += t;
      __syncthreads();
    }
    if (base + tid < N_NODES) rowptr[base + tid] = carry + sm[tid] - v; // exclusive
    int tot = sm[1023];
    __syncthreads();       // protect sm before next chunk overwrites it
    carry += tot;
  }
  if (tid == 0) rowptr[N_NODES] = carry;
}

__global__ __launch_bounds__(256) void k_scatter(const int* __restrict__ src,
                                                 const int* __restrict__ dst,
                                                 const int* __restrict__ rowptr,
                                                 int* __restrict__ fill,
                                                 int* __restrict__ csr_src){
  int e = blockIdx.x * 256 + threadIdx.x;
  if (e < N_EDGES){
    int d = dst[e];
    int pos = rowptr[d] + atomicAdd(&fill[d], 1);
    csr_src[pos] = src[e];
  }
}

// ---------------- node transform: h = x@W [N,256], alphas from x@A ----------------
// block = 256 threads = 4 waves; each wave computes 2 nodes (8 nodes/block).
// Wave lane l covers output columns l*4..l*4+3 of the 256-wide h row.

template<int F, bool DYNIN>
__global__ __launch_bounds__(256) void k_node(const void* __restrict__ xin_,
    const float* __restrict__ Wc, const float* __restrict__ Ac,
    const float* __restrict__ attS, const float* __restrict__ attD,
    float* __restrict__ hmat, float* __restrict__ alpha_s, float* __restrict__ alpha_d,
    const int* __restrict__ flag)
{
  __shared__ float xs[8][F];
  const int tid = threadIdx.x;
  const int base = blockIdx.x * 8;
  bool bf = false;
  if (DYNIN) bf = (*flag != 0);
  for (int idx = tid; idx < 8 * F; idx += 256){
    int nl = idx / F, k = idx % F;
    size_t g = (size_t)(base + nl) * F + k;
    xs[nl][k] = (DYNIN && bf) ? bf2f(((const unsigned short*)xin_)[g])
                              : ((const float*)xin_)[g];
  }
  __syncthreads();

  const int wave = tid >> 6, l = tid & 63;
  const float* x0 = xs[wave * 2];
  const float* x1 = xs[wave * 2 + 1];
  float4 acc0 = make_float4(0.f,0.f,0.f,0.f), acc1 = make_float4(0.f,0.f,0.f,0.f);
  #pragma unroll 4
  for (int k = 0; k < F; ++k){
    float4 wv = *(const float4*)(Wc + k * 256 + l * 4);
    float a0 = x0[k], a1 = x1[k];                           // LDS broadcast
    acc0.x += a0 * wv.x; acc0.y += a0 * wv.y; acc0.z += a0 * wv.z; acc0.w += a0 * wv.w;
    acc1.x += a1 * wv.x; acc1.y += a1 * wv.y; acc1.z += a1 * wv.z; acc1.w += a1 * wv.w;
  }
  const int n0 = base + wave * 2;
  *(float4*)(hmat + (size_t)n0 * 256 + l * 4)       = acc0;
  *(float4*)(hmat + (size_t)(n0 + 1) * 256 + l * 4) = acc1;

  // a = x@A [16], alphas: lanes split as (node nd = l>>5, k-half kq, j = l&15)
  const int j = l & 15, kq = (l >> 4) & 1, nd = l >> 5;
  const float* xr = xs[wave * 2 + nd];
  float a = 0.f;
  for (int k = kq * (F / 2); k < kq * (F / 2) + F / 2; ++k)
    a += xr[k] * Ac[k * 16 + j];
  a += __shfl_xor(a, 16);                 // combine k-halves -> full a[j] everywhere
  float ps = a * attS[j];
  float pd = a * attD[j];
  ps += __shfl_xor(ps, 1); ps += __shfl_xor(ps, 2);   // reduce over d within head
  pd += __shfl_xor(pd, 1); pd += __shfl_xor(pd, 2);
  if (((l & 3) == 0) && (kq == 0)){
    int hh = j >> 2;
    int n = base + wave * 2 + nd;
    alpha_s[n * 4 + hh] = ps;
    alpha_d[n * 4 + hh] = pd;
  }
}

// ---------------- aggregation: edge softmax + weighted sum per dst node ----------------
// block = 256 = 4 waves, one wave per dst node. Lane l: head hh=l>>4, channels (l&15)*4..
// Single pass: acc = sum exp(e)*h[src], den = sum exp(e); normalize at the end.

template<bool FINAL>
__global__ __launch_bounds__(256) void k_aggr(
    const float* __restrict__ hmat, const float* __restrict__ alpha_s,
    const float* __restrict__ alpha_d, const int* __restrict__ rowptr,
    const int* __restrict__ csr_src, const float* __restrict__ bias,
    void* __restrict__ out, const int* __restrict__ flag)
{
  const int tid = threadIdx.x;
  const int wave = tid >> 6, l = tid & 63;
  const int n = blockIdx.x * 4 + wave;
  const int hh = l >> 4;
  const float adv = alpha_d[n * 4 + hh];
  const int p0 = rowptr[n], p1 = rowptr[n + 1];
  float4 acc = make_float4(0.f,0.f,0.f,0.f);
  float den = 0.f;
  for (int p = p0; p < p1; ++p){
    int s = csr_src[p];                                   // wave-uniform broadcast
    float e = alpha_s[s * 4 + hh] + adv;
    e = (e >= 0.f) ? e : 0.2f * e;                        // leaky_relu slope 0.2
    float ex = __expf(e);
    den += ex;
    float4 hv = *(const float4*)(hmat + (size_t)s * 256 + l * 4);  // 1KB coalesced/wave
    acc.x += ex * hv.x; acc.y += ex * hv.y; acc.z += ex * hv.z; acc.w += ex * hv.w;
  }
  float r = (den > 0.f) ? (1.f / den) : 0.f;              // deg-0 guard -> 0
  acc.x *= r; acc.y *= r; acc.z *= r; acc.w *= r;
  // head-mean: sum over hh via xor 16/32, lanes 0..15 hold all-head sums
  acc.x += __shfl_xor(acc.x, 16); acc.y += __shfl_xor(acc.y, 16);
  acc.z += __shfl_xor(acc.z, 16); acc.w += __shfl_xor(acc.w, 16);
  acc.x += __shfl_xor(acc.x, 32); acc.y += __shfl_xor(acc.y, 32);
  acc.z += __shfl_xor(acc.z, 32); acc.w += __shfl_xor(acc.w, 32);
  if (l < 16){
    float vx = 0.25f * acc.x + bias[l * 4 + 0];
    float vy = 0.25f * acc.y + bias[l * 4 + 1];
    float vz = 0.25f * acc.z + bias[l * 4 + 2];
    float vw = 0.25f * acc.w + bias[l * 4 + 3];
    vx = (vx >= 0.f) ? vx : 0.1f * vx;                    // post-layer leaky 0.1
    vy = (vy >= 0.f) ? vy : 0.1f * vy;
    vz = (vz >= 0.f) ? vz : 0.1f * vz;
    vw = (vw >= 0.f) ? vw : 0.1f * vw;
    bool bf16out = false;
    if (FINAL) bf16out = (*flag != 0);
    if (FINAL && bf16out){
      ushort4 o = make_ushort4(f2bf(vx), f2bf(vy), f2bf(vz), f2bf(vw));
      *(ushort4*)((unsigned short*)out + (size_t)n * 64 + l * 4) = o;
    } else {
      *(float4*)((float*)out + (size_t)n * 64 + l * 4) = make_float4(vx, vy, vz, vw);
    }
  }
}

// ---------------- launch ----------------

extern "C" void kernel_launch(void* const* d_in, const int* in_sizes, int n_in,
                              void* d_out, int out_size, void* d_ws, size_t ws_size,
                              hipStream_t stream)
{
  const void* x  = d_in[0];
  const int* ei  = (const int*)d_in[1];
  const int* src = ei;
  const int* dst = ei + N_EDGES;

  char* ws = (char*)d_ws;                      // ~69.7 MB used
  float* hmat   = (float*)(ws);                // [N,256] f32, reused both layers
  float* x2     = (float*)(ws + 51200000);     // [N,64]  f32 layer-1 output
  float* as_    = (float*)(ws + 64000000);     // [N,4]
  float* ad_    = (float*)(ws + 64800000);     // [N,4]
  int*   deg    = (int*)  (ws + 65600000);     // [N]
  int*   fill   = (int*)  (ws + 65800000);     // [N]
  int*   rowptr = (int*)  (ws + 66000000);     // [N+1]
  int*   csr    = (int*)  (ws + 66200064);     // [E] src sorted by dst
  int*   flag   = (int*)  (ws + 69400064);     // dtype flag (1 = bf16)
  float* Wc1    = (float*)(ws + 69400128);     // [128*256]
  float* Ac1    = (float*)(ws + 69531200);     // [128*16]
  float* aSc1   = (float*)(ws + 69539392);     // [16]
  float* aDc1   = (float*)(ws + 69539456);     // [16]
  float* bc1    = (float*)(ws + 69539520);     // [64]
  float* Wc2    = (float*)(ws + 69539776);     // [64*256]
  float* Ac2    = (float*)(ws + 69605312);     // [64*16]
  float* aSc2   = (float*)(ws + 69609408);     // [16]
  float* aDc2   = (float*)(ws + 69609472);     // [16]
  float* bc2    = (float*)(ws + 69609536);     // [64]

  k_detect<<<1, 64, 0, stream>>>((const unsigned int*)x, flag);

  ParamPtrs P;
  P.src[0] = d_in[2];  P.dst[0] = Wc1;  P.len[0] = 128 * 256;
  P.src[1] = d_in[3];  P.dst[1] = Ac1;  P.len[1] = 128 * 16;
  P.src[2] = d_in[4];  P.dst[2] = aSc1; P.len[2] = 16;
  P.src[3] = d_in[5];  P.dst[3] = aDc1; P.len[3] = 16;
  P.src[4] = d_in[6];  P.dst[4] = bc1;  P.len[4] = 64;
  P.src[5] = d_in[7];  P.dst[5] = Wc2;  P.len[5] = 64 * 256;
  P.src[6] = d_in[8];  P.dst[6] = Ac2;  P.len[6] = 64 * 16;
  P.src[7] = d_in[9];  P.dst[7] = aSc2; P.len[7] = 16;
  P.src[8] = d_in[10]; P.dst[8] = aDc2; P.len[8] = 16;
  P.src[9] = d_in[11]; P.dst[9] = bc2;  P.len[9] = 64;
  k_params<<<dim3(128, 10), 256, 0, stream>>>(P, flag);

  hipMemsetAsync(deg,  0, N_NODES * sizeof(int), stream);
  hipMemsetAsync(fill, 0, N_NODES * sizeof(int), stream);
  k_hist   <<<(N_EDGES + 255) / 256, 256, 0, stream>>>(dst, deg);
  k_scan   <<<1, 1024, 0, stream>>>(deg, rowptr);
  k_scatter<<<(N_EDGES + 255) / 256, 256, 0, stream>>>(src, dst, rowptr, fill, csr);

  // layer 1 (Fin=128, input dtype per flag)
  k_node<128, true><<<N_NODES / 8, 256, 0, stream>>>(x, Wc1, Ac1, aSc1, aDc1, hmat, as_, ad_, flag);
  k_aggr<false>    <<<N_NODES / 4, 256, 0, stream>>>(hmat, as_, ad_, rowptr, csr, bc1, x2, flag);
  // layer 2 (Fin=64, f32 intermediate input)
  k_node<64, false><<<N_NODES / 8, 256, 0, stream>>>(x2, Wc2, Ac2, aSc2, aDc2, hmat, as_, ad_, flag);
  k_aggr<true>     <<<N_NODES / 4, 256, 0, stream>>>(hmat, as_, ad_, rowptr, csr, bc2, d_out, flag);
}

// Round 3
// 495.953 us; speedup vs baseline: 1.3576x; 1.3576x over previous
//
#include <hip/hip_runtime.h>

// GAT 2-layer fused pipeline for MI355X.
// N=50000 nodes, E=800000 edges, H=4 heads, C=64 channels, D=4 att dims.
// Float inputs/outputs: dtype (fp32 vs packed bf16) detected at runtime by k_detect;
// edge_index int32. Internal math fp32.
//
// Round-3 changes vs round-2 (which passed at 673 us):
//  - k_node: 8 nodes/wave (was 2) -> 4x less redundant W streaming (L2-BW bound
//    at 24.6 TB/s was the round-2 bottleneck: 3.2 GB -> 800 MB).
//  - alphas via precomputed Bs/Bd[k][h] = sum_d A[k,h*4+d]*att[h,d]  (k_prep).
//  - single-block scan -> two-level 3-kernel scan.
//  - k_aggr: 2-edge unroll for memory-level parallelism.

#define N_NODES 50000
#define N_EDGES 800000
#define NB_SCAN 196   // ceil(N_NODES/256)

__device__ __forceinline__ float bf2f(unsigned short u){
  return __uint_as_float(((unsigned int)u) << 16);
}
__device__ __forceinline__ unsigned short f2bf(float f){
  unsigned int u = __float_as_uint(f);
  u = (u + 0x7FFFu + ((u >> 16) & 1u)) >> 16;   // round-to-nearest-even
  return (unsigned short)u;
}

// ---------------- dtype probe ----------------
__global__ void k_detect(const unsigned int* __restrict__ xb, int* __restrict__ flag){
  int l = threadIdx.x;
  unsigned int w = xb[l] & 0xFFFFu;
  unsigned int e = (w >> 7) & 0xFFu;
  bool hit = (e >= 100u && e <= 135u);
  unsigned long long m = __ballot(hit);
  if (l == 0) *flag = (__popcll(m) > 40) ? 1 : 0;   // 1 = bf16 inputs
}

// ---------------- param conversion: all weights -> fp32 in ws ----------------
struct ParamPtrs { const void* src[10]; float* dst[10]; int len[10]; };

__global__ __launch_bounds__(256) void k_params(ParamPtrs P, const int* __restrict__ flag){
  const bool bf = (*flag != 0);
  const int a = blockIdx.y;
  const int i = blockIdx.x * 256 + threadIdx.x;
  if (i < P.len[a]){
    float v = bf ? bf2f(((const unsigned short*)P.src[a])[i]) : ((const float*)P.src[a])[i];
    P.dst[a][i] = v;
  }
}

// Bs[k][h] = sum_d A[k][h*4+d]*attS[h*4+d]; Bd likewise with attD.
__global__ __launch_bounds__(256) void k_prep(
    const float* __restrict__ Ac1, const float* __restrict__ aS1, const float* __restrict__ aD1,
    float* __restrict__ Bs1, float* __restrict__ Bd1,
    const float* __restrict__ Ac2, const float* __restrict__ aS2, const float* __restrict__ aD2,
    float* __restrict__ Bs2, float* __restrict__ Bd2)
{
  int t = blockIdx.x * 256 + threadIdx.x;
  if (t < 512){
    int k = t >> 2, h = t & 3;
    float s = 0.f, d = 0.f;
    for (int dd = 0; dd < 4; ++dd){
      float av = Ac1[k * 16 + h * 4 + dd];
      s += av * aS1[h * 4 + dd];
      d += av * aD1[h * 4 + dd];
    }
    Bs1[t] = s; Bd1[t] = d;
  } else if (t < 768){
    int u = t - 512, k = u >> 2, h = u & 3;
    float s = 0.f, d = 0.f;
    for (int dd = 0; dd < 4; ++dd){
      float av = Ac2[k * 16 + h * 4 + dd];
      s += av * aS2[h * 4 + dd];
      d += av * aD2[h * 4 + dd];
    }
    Bs2[u] = s; Bd2[u] = d;
  }
}

// ---------------- CSR build ----------------

__global__ __launch_bounds__(256) void k_hist(const int* __restrict__ dst,
                                              int* __restrict__ deg){
  int e = blockIdx.x * 256 + threadIdx.x;
  if (e < N_EDGES) atomicAdd(&deg[dst[e]], 1);
}

__global__ __launch_bounds__(256) void k_scan1(const int* __restrict__ deg,
                                               int* __restrict__ blocksum){
  int b = blockIdx.x, t = threadIdx.x, i = b * 256 + t;
  int v = (i < N_NODES) ? deg[i] : 0;
  for (int off = 1; off < 64; off <<= 1) v += __shfl_xor(v, off);
  __shared__ int sm[4];
  if ((t & 63) == 0) sm[t >> 6] = v;
  __syncthreads();
  if (t == 0) blocksum[b] = sm[0] + sm[1] + sm[2] + sm[3];
}

__global__ __launch_bounds__(256) void k_scan2(const int* __restrict__ blocksum,
                                               int* __restrict__ blockoff){
  __shared__ int sm[256];
  int t = threadIdx.x;
  int v = (t < NB_SCAN) ? blocksum[t] : 0;
  sm[t] = v;
  __syncthreads();
  for (int off = 1; off < 256; off <<= 1){
    int u = (t >= off) ? sm[t - off] : 0;
    __syncthreads();
    sm[t] += u;
    __syncthreads();
  }
  blockoff[t] = sm[t] - v;   // exclusive
}

__global__ __launch_bounds__(256) void k_scan3(const int* __restrict__ deg,
                                               const int* __restrict__ blockoff,
                                               int* __restrict__ rowptr){
  __shared__ int sm[256];
  int b = blockIdx.x, t = threadIdx.x, i = b * 256 + t;
  int v = (i < N_NODES) ? deg[i] : 0;
  sm[t] = v;
  __syncthreads();
  for (int off = 1; off < 256; off <<= 1){
    int u = (t >= off) ? sm[t - off] : 0;
    __syncthreads();
    sm[t] += u;
    __syncthreads();
  }
  if (i < N_NODES) rowptr[i] = blockoff[b] + sm[t] - v;
  if (i == 0) rowptr[N_NODES] = N_EDGES;
}

__global__ __launch_bounds__(256) void k_scatter(const int* __restrict__ src,
                                                 const int* __restrict__ dst,
                                                 const int* __restrict__ rowptr,
                                                 int* __restrict__ fill,
                                                 int* __restrict__ csr_src){
  int e = blockIdx.x * 256 + threadIdx.x;
  if (e < N_EDGES){
    int d = dst[e];
    int pos = rowptr[d] + atomicAdd(&fill[d], 1);
    csr_src[pos] = src[e];
  }
}

// ---------------- node transform: h = x@W [N,256] + alphas ----------------
// block = 256 = 4 waves; 8 nodes per wave (32 per block). Lane l covers output
// columns l*4..l*4+3. W row chunk loaded once per k, reused across 8 nodes.

template<int F, bool DYNIN>
__global__ __launch_bounds__(256) void k_node(const void* __restrict__ xin_,
    const float* __restrict__ Wc, const float* __restrict__ Bs, const float* __restrict__ Bd,
    float* __restrict__ hmat, float* __restrict__ alpha_s, float* __restrict__ alpha_d,
    const int* __restrict__ flag)
{
  __shared__ float xs[32][F];
  const int tid = threadIdx.x;
  const int base = blockIdx.x * 32;
  bool bf = false;
  if (DYNIN) bf = (*flag != 0);
  const int nvec = 32 * F / 4;
  for (int v = tid; v < nvec; v += 256){
    size_t gf = (size_t)base * F + (size_t)v * 4;
    size_t gmax = (size_t)N_NODES * F - 4;
    if (gf > gmax) gf = gmax;                      // tail-block clamp (stores guarded)
    float4 val;
    if (DYNIN && bf){
      ushort4 u = *(const ushort4*)((const unsigned short*)xin_ + gf);
      val = make_float4(bf2f(u.x), bf2f(u.y), bf2f(u.z), bf2f(u.w));
    } else {
      val = *(const float4*)((const float*)xin_ + gf);
    }
    *(float4*)&xs[0][v * 4] = val;                 // linear row-major copy
  }
  __syncthreads();

  const int wave = tid >> 6, l = tid & 63;
  const float* xw = &xs[wave * 8][0];
  float4 acc[8];
  #pragma unroll
  for (int nd = 0; nd < 8; ++nd) acc[nd] = make_float4(0.f,0.f,0.f,0.f);

  for (int kk = 0; kk < F; kk += 4){
    float xv[8][4];
    #pragma unroll
    for (int nd = 0; nd < 8; ++nd)
      *(float4*)xv[nd] = *(const float4*)(xw + nd * F + kk);   // ds_read_b128 broadcast
    #pragma unroll
    for (int j = 0; j < 4; ++j){
      float4 wv = *(const float4*)(Wc + (kk + j) * 256 + l * 4);
      #pragma unroll
      for (int nd = 0; nd < 8; ++nd){
        float xj = xv[nd][j];
        acc[nd].x += xj * wv.x; acc[nd].y += xj * wv.y;
        acc[nd].z += xj * wv.z; acc[nd].w += xj * wv.w;
      }
    }
  }
  #pragma unroll
  for (int nd = 0; nd < 8; ++nd){
    int n = base + wave * 8 + nd;
    if (n < N_NODES)
      *(float4*)(hmat + (size_t)n * 256 + l * 4) = acc[nd];
  }

  // alphas: lane l -> h = l&3, k-segment seg = l>>2 (16 segments of F/16)
  const int h = l & 3, seg = l >> 2;
  const int KS = F / 16;
  for (int nd = 0; nd < 8; ++nd){
    const float* xr = xw + nd * F;
    float s_ = 0.f, d_ = 0.f;
    #pragma unroll
    for (int kk = 0; kk < KS; ++kk){
      int k = seg * KS + kk;
      float xv_ = xr[k];
      s_ += xv_ * Bs[k * 4 + h];
      d_ += xv_ * Bd[k * 4 + h];
    }
    s_ += __shfl_xor(s_, 4);  s_ += __shfl_xor(s_, 8);
    s_ += __shfl_xor(s_, 16); s_ += __shfl_xor(s_, 32);
    d_ += __shfl_xor(d_, 4);  d_ += __shfl_xor(d_, 8);
    d_ += __shfl_xor(d_, 16); d_ += __shfl_xor(d_, 32);
    int n = base + wave * 8 + nd;
    if (l < 4 && n < N_NODES){
      alpha_s[n * 4 + l] = s_;
      alpha_d[n * 4 + l] = d_;
    }
  }
}

// ---------------- aggregation: edge softmax + weighted sum per dst ----------------
// block = 256 = 4 waves, one wave per dst node. Lane l: head hh=l>>4, 4 channels.
// 2-edge unroll: independent gather chains double memory-level parallelism.

template<bool FINAL>
__global__ __launch_bounds__(256) void k_aggr(
    const float* __restrict__ hmat, const float* __restrict__ alpha_s,
    const float* __restrict__ alpha_d, const int* __restrict__ rowptr,
    const int* __restrict__ csr_src, const float* __restrict__ bias,
    void* __restrict__ out, const int* __restrict__ flag)
{
  const int tid = threadIdx.x;
  const int wave = tid >> 6, l = tid & 63;
  const int n = blockIdx.x * 4 + wave;
  const int hh = l >> 4;
  const float adv = alpha_d[n * 4 + hh];
  const int p0 = rowptr[n], p1 = rowptr[n + 1];
  float4 acc = make_float4(0.f,0.f,0.f,0.f);
  float den = 0.f;
  int p = p0;
  if ((p1 - p0) & 1){
    int s = csr_src[p++];
    float e = alpha_s[s * 4 + hh] + adv;
    e = (e >= 0.f) ? e : 0.2f * e;
    float ex = __expf(e);
    float4 hv = *(const float4*)(hmat + (size_t)s * 256 + l * 4);
    den += ex;
    acc.x += ex * hv.x; acc.y += ex * hv.y; acc.z += ex * hv.z; acc.w += ex * hv.w;
  }
  for (; p < p1; p += 2){
    int s0 = csr_src[p], s1 = csr_src[p + 1];
    float a0 = alpha_s[s0 * 4 + hh];
    float a1 = alpha_s[s1 * 4 + hh];
    float4 h0 = *(const float4*)(hmat + (size_t)s0 * 256 + l * 4);
    float4 h1 = *(const float4*)(hmat + (size_t)s1 * 256 + l * 4);
    float e0 = a0 + adv; e0 = (e0 >= 0.f) ? e0 : 0.2f * e0;
    float e1 = a1 + adv; e1 = (e1 >= 0.f) ? e1 : 0.2f * e1;
    float ex0 = __expf(e0), ex1 = __expf(e1);
    den += ex0 + ex1;
    acc.x += ex0 * h0.x + ex1 * h1.x;
    acc.y += ex0 * h0.y + ex1 * h1.y;
    acc.z += ex0 * h0.z + ex1 * h1.z;
    acc.w += ex0 * h0.w + ex1 * h1.w;
  }
  float r = (den > 0.f) ? (1.f / den) : 0.f;
  acc.x *= r; acc.y *= r; acc.z *= r; acc.w *= r;
  acc.x += __shfl_xor(acc.x, 16); acc.y += __shfl_xor(acc.y, 16);
  acc.z += __shfl_xor(acc.z, 16); acc.w += __shfl_xor(acc.w, 16);
  acc.x += __shfl_xor(acc.x, 32); acc.y += __shfl_xor(acc.y, 32);
  acc.z += __shfl_xor(acc.z, 32); acc.w += __shfl_xor(acc.w, 32);
  if (l < 16){
    float vx = 0.25f * acc.x + bias[l * 4 + 0];
    float vy = 0.25f * acc.y + bias[l * 4 + 1];
    float vz = 0.25f * acc.z + bias[l * 4 + 2];
    float vw = 0.25f * acc.w + bias[l * 4 + 3];
    vx = (vx >= 0.f) ? vx : 0.1f * vx;
    vy = (vy >= 0.f) ? vy : 0.1f * vy;
    vz = (vz >= 0.f) ? vz : 0.1f * vz;
    vw = (vw >= 0.f) ? vw : 0.1f * vw;
    bool bf16out = false;
    if (FINAL) bf16out = (*flag != 0);
    if (FINAL && bf16out){
      ushort4 o = make_ushort4(f2bf(vx), f2bf(vy), f2bf(vz), f2bf(vw));
      *(ushort4*)((unsigned short*)out + (size_t)n * 64 + l * 4) = o;
    } else {
      *(float4*)((float*)out + (size_t)n * 64 + l * 4) = make_float4(vx, vy, vz, vw);
    }
  }
}

// ---------------- launch ----------------

extern "C" void kernel_launch(void* const* d_in, const int* in_sizes, int n_in,
                              void* d_out, int out_size, void* d_ws, size_t ws_size,
                              hipStream_t stream)
{
  const void* x  = d_in[0];
  const int* ei  = (const int*)d_in[1];
  const int* src = ei;
  const int* dst = ei + N_EDGES;

  char* ws = (char*)d_ws;                      // ~69.6 MB used
  float* hmat   = (float*)(ws);                // [N,256] f32, reused both layers
  float* x2     = (float*)(ws + 51200000);     // [N,64]  f32 layer-1 output
  float* as_    = (float*)(ws + 64000000);     // [N,4]
  float* ad_    = (float*)(ws + 64800000);     // [N,4]
  int*   deg    = (int*)  (ws + 65600000);     // [N]
  int*   fill   = (int*)  (ws + 65800000);     // [N]
  int*   rowptr = (int*)  (ws + 66000000);     // [N+1]
  int*   csr    = (int*)  (ws + 66200064);     // [E] src sorted by dst
  int*   flag   = (int*)  (ws + 69400064);     // dtype flag (1 = bf16)
  float* Wc1    = (float*)(ws + 69400128);     // [128*256]
  float* Ac1    = (float*)(ws + 69531200);     // [128*16]
  float* aSc1   = (float*)(ws + 69539392);     // [16]
  float* aDc1   = (float*)(ws + 69539456);     // [16]
  float* bc1    = (float*)(ws + 69539520);     // [64]
  float* Wc2    = (float*)(ws + 69539776);     // [64*256]
  float* Ac2    = (float*)(ws + 69605312);     // [64*16]
  float* aSc2   = (float*)(ws + 69609408);     // [16]
  float* aDc2   = (float*)(ws + 69609472);     // [16]
  float* bc2    = (float*)(ws + 69609536);     // [64]
  int*   bsum   = (int*)  (ws + 69609792);     // [256]
  int*   boff   = (int*)  (ws + 69610816);     // [256]
  float* Bs1    = (float*)(ws + 69611840);     // [128*4]
  float* Bd1    = (float*)(ws + 69613888);     // [128*4]
  float* Bs2    = (float*)(ws + 69615936);     // [64*4]
  float* Bd2    = (float*)(ws + 69616960);     // [64*4]

  k_detect<<<1, 64, 0, stream>>>((const unsigned int*)x, flag);

  ParamPtrs P;
  P.src[0] = d_in[2];  P.dst[0] = Wc1;  P.len[0] = 128 * 256;
  P.src[1] = d_in[3];  P.dst[1] = Ac1;  P.len[1] = 128 * 16;
  P.src[2] = d_in[4];  P.dst[2] = aSc1; P.len[2] = 16;
  P.src[3] = d_in[5];  P.dst[3] = aDc1; P.len[3] = 16;
  P.src[4] = d_in[6];  P.dst[4] = bc1;  P.len[4] = 64;
  P.src[5] = d_in[7];  P.dst[5] = Wc2;  P.len[5] = 64 * 256;
  P.src[6] = d_in[8];  P.dst[6] = Ac2;  P.len[6] = 64 * 16;
  P.src[7] = d_in[9];  P.dst[7] = aSc2; P.len[7] = 16;
  P.src[8] = d_in[10]; P.dst[8] = aDc2; P.len[8] = 16;
  P.src[9] = d_in[11]; P.dst[9] = bc2;  P.len[9] = 64;
  k_params<<<dim3(128, 10), 256, 0, stream>>>(P, flag);
  k_prep  <<<3, 256, 0, stream>>>(Ac1, aSc1, aDc1, Bs1, Bd1, Ac2, aSc2, aDc2, Bs2, Bd2);

  hipMemsetAsync(deg,  0, N_NODES * sizeof(int), stream);
  hipMemsetAsync(fill, 0, N_NODES * sizeof(int), stream);
  k_hist   <<<(N_EDGES + 255) / 256, 256, 0, stream>>>(dst, deg);
  k_scan1  <<<NB_SCAN, 256, 0, stream>>>(deg, bsum);
  k_scan2  <<<1, 256, 0, stream>>>(bsum, boff);
  k_scan3  <<<NB_SCAN, 256, 0, stream>>>(deg, boff, rowptr);
  k_scatter<<<(N_EDGES + 255) / 256, 256, 0, stream>>>(src, dst, rowptr, fill, csr);

  // layer 1 (Fin=128, input dtype per flag)
  k_node<128, true><<<(N_NODES + 31) / 32, 256, 0, stream>>>(x, Wc1, Bs1, Bd1, hmat, as_, ad_, flag);
  k_aggr<false>    <<<N_NODES / 4, 256, 0, stream>>>(hmat, as_, ad_, rowptr, csr, bc1, x2, flag);
  // layer 2 (Fin=64, f32 intermediate input)
  k_node<64, false><<<(N_NODES + 31) / 32, 256, 0, stream>>>(x2, Wc2, Bs2, Bd2, hmat, as_, ad_, flag);
  k_aggr<true>     <<<N_NODES / 4, 256, 0, stream>>>(hmat, as_, ad_, rowptr, csr, bc2, d_out, flag);
}

// Round 6
// 388.552 us; speedup vs baseline: 1.7329x; 1.2764x over previous
//
#include <hip/hip_runtime.h>

// GAT 2-layer fused pipeline for MI355X.
// N=50000 nodes, E=800000 edges, H=4 heads, C=64 channels, D=4 att dims.
// Float inputs/outputs: dtype (fp32 vs packed bf16) detected at runtime by k_detect;
// edge_index int32. Internal math fp32; h matrix stored fp16 (gather traffic /2).
//
// Round-6 = round-4 resubmitted again (rounds 4 and 5 both died on container
// acquisition; source never ran). Changes vs round-3 (passed at 496 us, k_aggr
// 117 us x2 fabric-BW-bound):
//  - hmat fp32 -> fp16 (25.6 MB): halves the per-edge 1KB gather, fits ~L2.
//  - k_aggr: 4-edge unroll for memory-level parallelism on the gather latency.
//  - two memsets -> one k_zero launch.

#define N_NODES 50000
#define N_EDGES 800000
#define NB_SCAN 196   // ceil(N_NODES/256)

typedef _Float16 half4 __attribute__((ext_vector_type(4)));

__device__ __forceinline__ float bf2f(unsigned short u){
  return __uint_as_float(((unsigned int)u) << 16);
}
__device__ __forceinline__ unsigned short f2bf(float f){
  unsigned int u = __float_as_uint(f);
  u = (u + 0x7FFFu + ((u >> 16) & 1u)) >> 16;   // round-to-nearest-even
  return (unsigned short)u;
}

// ---------------- dtype probe ----------------
__global__ void k_detect(const unsigned int* __restrict__ xb, int* __restrict__ flag){
  int l = threadIdx.x;
  unsigned int w = xb[l] & 0xFFFFu;
  unsigned int e = (w >> 7) & 0xFFu;
  bool hit = (e >= 100u && e <= 135u);
  unsigned long long m = __ballot(hit);
  if (l == 0) *flag = (__popcll(m) > 40) ? 1 : 0;   // 1 = bf16 inputs
}

// ---------------- param conversion: all weights -> fp32 in ws ----------------
struct ParamPtrs { const void* src[10]; float* dst[10]; int len[10]; };

__global__ __launch_bounds__(256) void k_params(ParamPtrs P, const int* __restrict__ flag){
  const bool bf = (*flag != 0);
  const int a = blockIdx.y;
  const int i = blockIdx.x * 256 + threadIdx.x;
  if (i < P.len[a]){
    float v = bf ? bf2f(((const unsigned short*)P.src[a])[i]) : ((const float*)P.src[a])[i];
    P.dst[a][i] = v;
  }
}

// Bs[k][h] = sum_d A[k][h*4+d]*attS[h*4+d]; Bd likewise with attD.
__global__ __launch_bounds__(256) void k_prep(
    const float* __restrict__ Ac1, const float* __restrict__ aS1, const float* __restrict__ aD1,
    float* __restrict__ Bs1, float* __restrict__ Bd1,
    const float* __restrict__ Ac2, const float* __restrict__ aS2, const float* __restrict__ aD2,
    float* __restrict__ Bs2, float* __restrict__ Bd2)
{
  int t = blockIdx.x * 256 + threadIdx.x;
  if (t < 512){
    int k = t >> 2, h = t & 3;
    float s = 0.f, d = 0.f;
    for (int dd = 0; dd < 4; ++dd){
      float av = Ac1[k * 16 + h * 4 + dd];
      s += av * aS1[h * 4 + dd];
      d += av * aD1[h * 4 + dd];
    }
    Bs1[t] = s; Bd1[t] = d;
  } else if (t < 768){
    int u = t - 512, k = u >> 2, h = u & 3;
    float s = 0.f, d = 0.f;
    for (int dd = 0; dd < 4; ++dd){
      float av = Ac2[k * 16 + h * 4 + dd];
      s += av * aS2[h * 4 + dd];
      d += av * aD2[h * 4 + dd];
    }
    Bs2[u] = s; Bd2[u] = d;
  }
}

// ---------------- CSR build ----------------

__global__ __launch_bounds__(256) void k_zero(int* __restrict__ deg, int* __restrict__ fill){
  int i = blockIdx.x * 256 + threadIdx.x;
  if (i < N_NODES){ deg[i] = 0; fill[i] = 0; }
}

__global__ __launch_bounds__(256) void k_hist(const int* __restrict__ dst,
                                              int* __restrict__ deg){
  int e = blockIdx.x * 256 + threadIdx.x;
  if (e < N_EDGES) atomicAdd(&deg[dst[e]], 1);
}

__global__ __launch_bounds__(256) void k_scan1(const int* __restrict__ deg,
                                               int* __restrict__ blocksum){
  int b = blockIdx.x, t = threadIdx.x, i = b * 256 + t;
  int v = (i < N_NODES) ? deg[i] : 0;
  for (int off = 1; off < 64; off <<= 1) v += __shfl_xor(v, off);
  __shared__ int sm[4];
  if ((t & 63) == 0) sm[t >> 6] = v;
  __syncthreads();
  if (t == 0) blocksum[b] = sm[0] + sm[1] + sm[2] + sm[3];
}

__global__ __launch_bounds__(256) void k_scan2(const int* __restrict__ blocksum,
                                               int* __restrict__ blockoff){
  __shared__ int sm[256];
  int t = threadIdx.x;
  int v = (t < NB_SCAN) ? blocksum[t] : 0;
  sm[t] = v;
  __syncthreads();
  for (int off = 1; off < 256; off <<= 1){
    int u = (t >= off) ? sm[t - off] : 0;
    __syncthreads();
    sm[t] += u;
    __syncthreads();
  }
  blockoff[t] = sm[t] - v;   // exclusive
}

__global__ __launch_bounds__(256) void k_scan3(const int* __restrict__ deg,
                                               const int* __restrict__ blockoff,
                                               int* __restrict__ rowptr){
  __shared__ int sm[256];
  int b = blockIdx.x, t = threadIdx.x, i = b * 256 + t;
  int v = (i < N_NODES) ? deg[i] : 0;
  sm[t] = v;
  __syncthreads();
  for (int off = 1; off < 256; off <<= 1){
    int u = (t >= off) ? sm[t - off] : 0;
    __syncthreads();
    sm[t] += u;
    __syncthreads();
  }
  if (i < N_NODES) rowptr[i] = blockoff[b] + sm[t] - v;
  if (i == 0) rowptr[N_NODES] = N_EDGES;
}

__global__ __launch_bounds__(256) void k_scatter(const int* __restrict__ src,
                                                 const int* __restrict__ dst,
                                                 const int* __restrict__ rowptr,
                                                 int* __restrict__ fill,
                                                 int* __restrict__ csr_src){
  int e = blockIdx.x * 256 + threadIdx.x;
  if (e < N_EDGES){
    int d = dst[e];
    int pos = rowptr[d] + atomicAdd(&fill[d], 1);
    csr_src[pos] = src[e];
  }
}

// ---------------- node transform: h = x@W [N,256] (fp16 out) + alphas ----------------
// block = 256 = 4 waves; 8 nodes per wave (32 per block). Lane l covers output
// columns l*4..l*4+3. W row chunk loaded once per k, reused across 8 nodes.

template<int F, bool DYNIN>
__global__ __launch_bounds__(256) void k_node(const void* __restrict__ xin_,
    const float* __restrict__ Wc, const float* __restrict__ Bs, const float* __restrict__ Bd,
    _Float16* __restrict__ hmat, float* __restrict__ alpha_s, float* __restrict__ alpha_d,
    const int* __restrict__ flag)
{
  __shared__ float xs[32][F];
  const int tid = threadIdx.x;
  const int base = blockIdx.x * 32;
  bool bf = false;
  if (DYNIN) bf = (*flag != 0);
  const int nvec = 32 * F / 4;
  for (int v = tid; v < nvec; v += 256){
    size_t gf = (size_t)base * F + (size_t)v * 4;
    size_t gmax = (size_t)N_NODES * F - 4;
    if (gf > gmax) gf = gmax;                      // tail-block clamp (stores guarded)
    float4 val;
    if (DYNIN && bf){
      ushort4 u = *(const ushort4*)((const unsigned short*)xin_ + gf);
      val = make_float4(bf2f(u.x), bf2f(u.y), bf2f(u.z), bf2f(u.w));
    } else {
      val = *(const float4*)((const float*)xin_ + gf);
    }
    *(float4*)&xs[0][v * 4] = val;                 // linear row-major copy
  }
  __syncthreads();

  const int wave = tid >> 6, l = tid & 63;
  const float* xw = &xs[wave * 8][0];
  float4 acc[8];
  #pragma unroll
  for (int nd = 0; nd < 8; ++nd) acc[nd] = make_float4(0.f,0.f,0.f,0.f);

  for (int kk = 0; kk < F; kk += 4){
    float xv[8][4];
    #pragma unroll
    for (int nd = 0; nd < 8; ++nd)
      *(float4*)xv[nd] = *(const float4*)(xw + nd * F + kk);   // ds_read_b128 broadcast
    #pragma unroll
    for (int j = 0; j < 4; ++j){
      float4 wv = *(const float4*)(Wc + (kk + j) * 256 + l * 4);
      #pragma unroll
      for (int nd = 0; nd < 8; ++nd){
        float xj = xv[nd][j];
        acc[nd].x += xj * wv.x; acc[nd].y += xj * wv.y;
        acc[nd].z += xj * wv.z; acc[nd].w += xj * wv.w;
      }
    }
  }
  #pragma unroll
  for (int nd = 0; nd < 8; ++nd){
    int n = base + wave * 8 + nd;
    if (n < N_NODES){
      half4 o;
      o.x = (_Float16)acc[nd].x; o.y = (_Float16)acc[nd].y;
      o.z = (_Float16)acc[nd].z; o.w = (_Float16)acc[nd].w;
      *(half4*)(hmat + (size_t)n * 256 + l * 4) = o;
    }
  }

  // alphas: lane l -> h = l&3, k-segment seg = l>>2 (16 segments of F/16)
  const int h = l & 3, seg = l >> 2;
  const int KS = F / 16;
  for (int nd = 0; nd < 8; ++nd){
    const float* xr = xw + nd * F;
    float s_ = 0.f, d_ = 0.f;
    #pragma unroll
    for (int kk = 0; kk < KS; ++kk){
      int k = seg * KS + kk;
      float xv_ = xr[k];
      s_ += xv_ * Bs[k * 4 + h];
      d_ += xv_ * Bd[k * 4 + h];
    }
    s_ += __shfl_xor(s_, 4);  s_ += __shfl_xor(s_, 8);
    s_ += __shfl_xor(s_, 16); s_ += __shfl_xor(s_, 32);
    d_ += __shfl_xor(d_, 4);  d_ += __shfl_xor(d_, 8);
    d_ += __shfl_xor(d_, 16); d_ += __shfl_xor(d_, 32);
    int n = base + wave * 8 + nd;
    if (l < 4 && n < N_NODES){
      alpha_s[n * 4 + l] = s_;
      alpha_d[n * 4 + l] = d_;
    }
  }
}

// ---------------- aggregation: edge softmax + weighted sum per dst ----------------
// block = 256 = 4 waves, one wave per dst node. Lane l: head hh=l>>4, 4 channels.
// 4-edge unroll: independent gather chains (8B fp16 loads) for MLP.

template<bool FINAL>
__global__ __launch_bounds__(256) void k_aggr(
    const _Float16* __restrict__ hmat, const float* __restrict__ alpha_s,
    const float* __restrict__ alpha_d, const int* __restrict__ rowptr,
    const int* __restrict__ csr_src, const float* __restrict__ bias,
    void* __restrict__ out, const int* __restrict__ flag)
{
  const int tid = threadIdx.x;
  const int wave = tid >> 6, l = tid & 63;
  const int n = blockIdx.x * 4 + wave;
  const int hh = l >> 4;
  const float adv = alpha_d[n * 4 + hh];
  const int p0 = rowptr[n], p1 = rowptr[n + 1];
  float4 acc = make_float4(0.f,0.f,0.f,0.f);
  float den = 0.f;
  int p = p0;
  for (; p + 4 <= p1; p += 4){
    int s0 = csr_src[p],     s1 = csr_src[p + 1];
    int s2 = csr_src[p + 2], s3 = csr_src[p + 3];
    float a0 = alpha_s[s0 * 4 + hh], a1 = alpha_s[s1 * 4 + hh];
    float a2 = alpha_s[s2 * 4 + hh], a3 = alpha_s[s3 * 4 + hh];
    half4 h0 = *(const half4*)(hmat + (size_t)s0 * 256 + l * 4);
    half4 h1 = *(const half4*)(hmat + (size_t)s1 * 256 + l * 4);
    half4 h2 = *(const half4*)(hmat + (size_t)s2 * 256 + l * 4);
    half4 h3 = *(const half4*)(hmat + (size_t)s3 * 256 + l * 4);
    float e0 = a0 + adv; e0 = (e0 >= 0.f) ? e0 : 0.2f * e0;
    float e1 = a1 + adv; e1 = (e1 >= 0.f) ? e1 : 0.2f * e1;
    float e2 = a2 + adv; e2 = (e2 >= 0.f) ? e2 : 0.2f * e2;
    float e3 = a3 + adv; e3 = (e3 >= 0.f) ? e3 : 0.2f * e3;
    float ex0 = __expf(e0), ex1 = __expf(e1), ex2 = __expf(e2), ex3 = __expf(e3);
    den += (ex0 + ex1) + (ex2 + ex3);
    acc.x += ex0 * (float)h0.x + ex1 * (float)h1.x + ex2 * (float)h2.x + ex3 * (float)h3.x;
    acc.y += ex0 * (float)h0.y + ex1 * (float)h1.y + ex2 * (float)h2.y + ex3 * (float)h3.y;
    acc.z += ex0 * (float)h0.z + ex1 * (float)h1.z + ex2 * (float)h2.z + ex3 * (float)h3.z;
    acc.w += ex0 * (float)h0.w + ex1 * (float)h1.w + ex2 * (float)h2.w + ex3 * (float)h3.w;
  }
  for (; p < p1; ++p){
    int s = csr_src[p];
    float e = alpha_s[s * 4 + hh] + adv;
    e = (e >= 0.f) ? e : 0.2f * e;
    float ex = __expf(e);
    half4 hv = *(const half4*)(hmat + (size_t)s * 256 + l * 4);
    den += ex;
    acc.x += ex * (float)hv.x; acc.y += ex * (float)hv.y;
    acc.z += ex * (float)hv.z; acc.w += ex * (float)hv.w;
  }
  float r = (den > 0.f) ? (1.f / den) : 0.f;
  acc.x *= r; acc.y *= r; acc.z *= r; acc.w *= r;
  acc.x += __shfl_xor(acc.x, 16); acc.y += __shfl_xor(acc.y, 16);
  acc.z += __shfl_xor(acc.z, 16); acc.w += __shfl_xor(acc.w, 16);
  acc.x += __shfl_xor(acc.x, 32); acc.y += __shfl_xor(acc.y, 32);
  acc.z += __shfl_xor(acc.z, 32); acc.w += __shfl_xor(acc.w, 32);
  if (l < 16){
    float vx = 0.25f * acc.x + bias[l * 4 + 0];
    float vy = 0.25f * acc.y + bias[l * 4 + 1];
    float vz = 0.25f * acc.z + bias[l * 4 + 2];
    float vw = 0.25f * acc.w + bias[l * 4 + 3];
    vx = (vx >= 0.f) ? vx : 0.1f * vx;
    vy = (vy >= 0.f) ? vy : 0.1f * vy;
    vz = (vz >= 0.f) ? vz : 0.1f * vz;
    vw = (vw >= 0.f) ? vw : 0.1f * vw;
    bool bf16out = false;
    if (FINAL) bf16out = (*flag != 0);
    if (FINAL && bf16out){
      ushort4 o = make_ushort4(f2bf(vx), f2bf(vy), f2bf(vz), f2bf(vw));
      *(ushort4*)((unsigned short*)out + (size_t)n * 64 + l * 4) = o;
    } else {
      *(float4*)((float*)out + (size_t)n * 64 + l * 4) = make_float4(vx, vy, vz, vw);
    }
  }
}

// ---------------- launch ----------------

extern "C" void kernel_launch(void* const* d_in, const int* in_sizes, int n_in,
                              void* d_out, int out_size, void* d_ws, size_t ws_size,
                              hipStream_t stream)
{
  const void* x  = d_in[0];
  const int* ei  = (const int*)d_in[1];
  const int* src = ei;
  const int* dst = ei + N_EDGES;

  char* ws = (char*)d_ws;                      // ~69.6 MB used
  _Float16* hmat = (_Float16*)(ws);            // [N,256] fp16, reused both layers
  float* x2     = (float*)(ws + 51200000);     // [N,64]  f32 layer-1 output
  float* as_    = (float*)(ws + 64000000);     // [N,4]
  float* ad_    = (float*)(ws + 64800000);     // [N,4]
  int*   deg    = (int*)  (ws + 65600000);     // [N]
  int*   fill   = (int*)  (ws + 65800000);     // [N]
  int*   rowptr = (int*)  (ws + 66000000);     // [N+1]
  int*   csr    = (int*)  (ws + 66200064);     // [E] src sorted by dst
  int*   flag   = (int*)  (ws + 69400064);     // dtype flag (1 = bf16)
  float* Wc1    = (float*)(ws + 69400128);     // [128*256]
  float* Ac1    = (float*)(ws + 69531200);     // [128*16]
  float* aSc1   = (float*)(ws + 69539392);     // [16]
  float* aDc1   = (float*)(ws + 69539456);     // [16]
  float* bc1    = (float*)(ws + 69539520);     // [64]
  float* Wc2    = (float*)(ws + 69539776);     // [64*256]
  float* Ac2    = (float*)(ws + 69605312);     // [64*16]
  float* aSc2   = (float*)(ws + 69609408);     // [16]
  float* aDc2   = (float*)(ws + 69609472);     // [16]
  float* bc2    = (float*)(ws + 69609536);     // [64]
  int*   bsum   = (int*)  (ws + 69609792);     // [256]
  int*   boff   = (int*)  (ws + 69610816);     // [256]
  float* Bs1    = (float*)(ws + 69611840);     // [128*4]
  float* Bd1    = (float*)(ws + 69613888);     // [128*4]
  float* Bs2    = (float*)(ws + 69615936);     // [64*4]
  float* Bd2    = (float*)(ws + 69616960);     // [64*4]

  k_detect<<<1, 64, 0, stream>>>((const unsigned int*)x, flag);

  ParamPtrs P;
  P.src[0] = d_in[2];  P.dst[0] = Wc1;  P.len[0] = 128 * 256;
  P.src[1] = d_in[3];  P.dst[1] = Ac1;  P.len[1] = 128 * 16;
  P.src[2] = d_in[4];  P.dst[2] = aSc1; P.len[2] = 16;
  P.src[3] = d_in[5];  P.dst[3] = aDc1; P.len[3] = 16;
  P.src[4] = d_in[6];  P.dst[4] = bc1;  P.len[4] = 64;
  P.src[5] = d_in[7];  P.dst[5] = Wc2;  P.len[5] = 64 * 256;
  P.src[6] = d_in[8];  P.dst[6] = Ac2;  P.len[6] = 64 * 16;
  P.src[7] = d_in[9];  P.dst[7] = aSc2; P.len[7] = 16;
  P.src[8] = d_in[10]; P.dst[8] = aDc2; P.len[8] = 16;
  P.src[9] = d_in[11]; P.dst[9] = bc2;  P.len[9] = 64;
  k_params<<<dim3(128, 10), 256, 0, stream>>>(P, flag);
  k_prep  <<<3, 256, 0, stream>>>(Ac1, aSc1, aDc1, Bs1, Bd1, Ac2, aSc2, aDc2, Bs2, Bd2);

  k_zero   <<<NB_SCAN, 256, 0, stream>>>(deg, fill);
  k_hist   <<<(N_EDGES + 255) / 256, 256, 0, stream>>>(dst, deg);
  k_scan1  <<<NB_SCAN, 256, 0, stream>>>(deg, bsum);
  k_scan2  <<<1, 256, 0, stream>>>(bsum, boff);
  k_scan3  <<<NB_SCAN, 256, 0, stream>>>(deg, boff, rowptr);
  k_scatter<<<(N_EDGES + 255) / 256, 256, 0, stream>>>(src, dst, rowptr, fill, csr);

  // layer 1 (Fin=128, input dtype per flag)
  k_node<128, true><<<(N_NODES + 31) / 32, 256, 0, stream>>>(x, Wc1, Bs1, Bd1, hmat, as_, ad_, flag);
  k_aggr<false>    <<<N_NODES / 4, 256, 0, stream>>>(hmat, as_, ad_, rowptr, csr, bc1, x2, flag);
  // layer 2 (Fin=64, f32 intermediate input)
  k_node<64, false><<<(N_NODES + 31) / 32, 256, 0, stream>>>(x2, Wc2, Bs2, Bd2, hmat, as_, ad_, flag);
  k_aggr<true>     <<<N_NODES / 4, 256, 0, stream>>>(hmat, as_, ad_, rowptr, csr, bc2, d_out, flag);
}

// Round 9
// 362.927 us; speedup vs baseline: 1.8553x; 1.0706x over previous
//
#include <hip/hip_runtime.h>

// GAT 2-layer fused pipeline for MI355X.
// N=50000 nodes, E=800000 edges, H=4 heads, C=64 channels, D=4 att dims.
// Inputs bf16 (runtime-detected, fp32 fallback); edge_index int32.
// Internal: fp32 math, h matrix fp16.
//
// Round-9 = round-7 source, third submission (rounds 7/8 died on container
// acquisition — same infra signature that hit rounds 4/5 before the identical
// source passed in round 6). Changes vs round-6 (passed 388.6 us; k_node<128>
// top at 68 us, VALU-stall-bound):
//  - layer-1 node kernel -> MFMA (mfma_f32_16x16x32_bf16): 16 nodes/wave,
//    W pre-swizzled to B-fragment layout (k_wswz), x staged bf16 in LDS.
//    A[m=lane&15][k=quad*8+j]; C/D col=lane&15,row=quad*4+reg (m89).
//  - layer-2 node kernel unchanged (fp32 vector path).

#define N_NODES 50000
#define N_EDGES 800000
#define NB_SCAN 196   // ceil(N_NODES/256)

typedef _Float16 half4 __attribute__((ext_vector_type(4)));
typedef __attribute__((ext_vector_type(8))) short short8;     // 8 bf16
typedef __attribute__((ext_vector_type(4))) float f32x4;
typedef __attribute__((ext_vector_type(8))) unsigned short ushort8;

__device__ __forceinline__ float bf2f(unsigned short u){
  return __uint_as_float(((unsigned int)u) << 16);
}
__device__ __forceinline__ unsigned short f2bf(float f){
  unsigned int u = __float_as_uint(f);
  u = (u + 0x7FFFu + ((u >> 16) & 1u)) >> 16;   // round-to-nearest-even
  return (unsigned short)u;
}

// ---------------- dtype probe ----------------
__global__ void k_detect(const unsigned int* __restrict__ xb, int* __restrict__ flag){
  int l = threadIdx.x;
  unsigned int w = xb[l] & 0xFFFFu;
  unsigned int e = (w >> 7) & 0xFFu;
  bool hit = (e >= 100u && e <= 135u);
  unsigned long long m = __ballot(hit);
  if (l == 0) *flag = (__popcll(m) > 40) ? 1 : 0;   // 1 = bf16 inputs
}

// ---------------- param conversion: weights -> fp32 in ws ----------------
struct ParamPtrs { const void* src[10]; float* dst[10]; int len[10]; };

__global__ __launch_bounds__(256) void k_params(ParamPtrs P, const int* __restrict__ flag){
  const bool bf = (*flag != 0);
  const int a = blockIdx.y;
  const int i = blockIdx.x * 256 + threadIdx.x;
  if (i < P.len[a]){
    float v = bf ? bf2f(((const unsigned short*)P.src[a])[i]) : ((const float*)P.src[a])[i];
    P.dst[a][i] = v;
  }
}

// W1 [128x256] -> bf16 B-fragment layout for mfma_f32_16x16x32_bf16:
// Wb[((nt*4 + kt)*64 + lane)*8 + j] = W1[k = kt*32 + (lane>>4)*8 + j][n = nt*16 + (lane&15)]
__global__ __launch_bounds__(256) void k_wswz(const void* __restrict__ W1,
                                              unsigned short* __restrict__ Wb,
                                              const int* __restrict__ flag){
  int t = blockIdx.x * 256 + threadIdx.x;        // 0..32767
  int j = t & 7, lane = (t >> 3) & 63, kt = (t >> 9) & 3, nt = t >> 11;
  int k = kt * 32 + (lane >> 4) * 8 + j;
  int n = nt * 16 + (lane & 15);
  unsigned short v;
  if (*flag) v = ((const unsigned short*)W1)[k * 256 + n];
  else       v = f2bf(((const float*)W1)[k * 256 + n]);
  Wb[t] = v;
}

// Bs[k][h] = sum_d A[k][h*4+d]*attS[h*4+d]; Bd likewise with attD.
__global__ __launch_bounds__(256) void k_prep(
    const float* __restrict__ Ac1, const float* __restrict__ aS1, const float* __restrict__ aD1,
    float* __restrict__ Bs1, float* __restrict__ Bd1,
    const float* __restrict__ Ac2, const float* __restrict__ aS2, const float* __restrict__ aD2,
    float* __restrict__ Bs2, float* __restrict__ Bd2)
{
  int t = blockIdx.x * 256 + threadIdx.x;
  if (t < 512){
    int k = t >> 2, h = t & 3;
    float s = 0.f, d = 0.f;
    for (int dd = 0; dd < 4; ++dd){
      float av = Ac1[k * 16 + h * 4 + dd];
      s += av * aS1[h * 4 + dd];
      d += av * aD1[h * 4 + dd];
    }
    Bs1[t] = s; Bd1[t] = d;
  } else if (t < 768){
    int u = t - 512, k = u >> 2, h = u & 3;
    float s = 0.f, d = 0.f;
    for (int dd = 0; dd < 4; ++dd){
      float av = Ac2[k * 16 + h * 4 + dd];
      s += av * aS2[h * 4 + dd];
      d += av * aD2[h * 4 + dd];
    }
    Bs2[u] = s; Bd2[u] = d;
  }
}

// ---------------- CSR build ----------------

__global__ __launch_bounds__(256) void k_zero(int* __restrict__ deg, int* __restrict__ fill){
  int i = blockIdx.x * 256 + threadIdx.x;
  if (i < N_NODES){ deg[i] = 0; fill[i] = 0; }
}

__global__ __launch_bounds__(256) void k_hist(const int* __restrict__ dst,
                                              int* __restrict__ deg){
  int e = blockIdx.x * 256 + threadIdx.x;
  if (e < N_EDGES) atomicAdd(&deg[dst[e]], 1);
}

__global__ __launch_bounds__(256) void k_scan1(const int* __restrict__ deg,
                                               int* __restrict__ blocksum){
  int b = blockIdx.x, t = threadIdx.x, i = b * 256 + t;
  int v = (i < N_NODES) ? deg[i] : 0;
  for (int off = 1; off < 64; off <<= 1) v += __shfl_xor(v, off);
  __shared__ int sm[4];
  if ((t & 63) == 0) sm[t >> 6] = v;
  __syncthreads();
  if (t == 0) blocksum[b] = sm[0] + sm[1] + sm[2] + sm[3];
}

__global__ __launch_bounds__(256) void k_scan2(const int* __restrict__ blocksum,
                                               int* __restrict__ blockoff){
  __shared__ int sm[256];
  int t = threadIdx.x;
  int v = (t < NB_SCAN) ? blocksum[t] : 0;
  sm[t] = v;
  __syncthreads();
  for (int off = 1; off < 256; off <<= 1){
    int u = (t >= off) ? sm[t - off] : 0;
    __syncthreads();
    sm[t] += u;
    __syncthreads();
  }
  blockoff[t] = sm[t] - v;   // exclusive
}

__global__ __launch_bounds__(256) void k_scan3(const int* __restrict__ deg,
                                               const int* __restrict__ blockoff,
                                               int* __restrict__ rowptr){
  __shared__ int sm[256];
  int b = blockIdx.x, t = threadIdx.x, i = b * 256 + t;
  int v = (i < N_NODES) ? deg[i] : 0;
  sm[t] = v;
  __syncthreads();
  for (int off = 1; off < 256; off <<= 1){
    int u = (t >= off) ? sm[t - off] : 0;
    __syncthreads();
    sm[t] += u;
    __syncthreads();
  }
  if (i < N_NODES) rowptr[i] = blockoff[b] + sm[t] - v;
  if (i == 0) rowptr[N_NODES] = N_EDGES;
}

__global__ __launch_bounds__(256) void k_scatter(const int* __restrict__ src,
                                                 const int* __restrict__ dst,
                                                 const int* __restrict__ rowptr,
                                                 int* __restrict__ fill,
                                                 int* __restrict__ csr_src){
  int e = blockIdx.x * 256 + threadIdx.x;
  if (e < N_EDGES){
    int d = dst[e];
    int pos = rowptr[d] + atomicAdd(&fill[d], 1);
    csr_src[pos] = src[e];
  }
}

// ---------------- layer-1 node transform via MFMA ----------------
// block = 256 = 4 waves, 16 nodes/wave (64/block). h = x@W1 via
// mfma_f32_16x16x32_bf16 (fp32 accum), fp16 store. Alphas fp32 vector path.

__global__ __launch_bounds__(256) void k_node1(const void* __restrict__ xin_,
    const unsigned short* __restrict__ Wb,
    const float* __restrict__ Bs, const float* __restrict__ Bd,
    _Float16* __restrict__ hmat, float* __restrict__ alpha_s, float* __restrict__ alpha_d,
    const int* __restrict__ flag)
{
  __shared__ unsigned short xs[64 * 136];  // 64 rows x 128 bf16, stride 136 (16B pad)
  const int tid = threadIdx.x;
  const int base = blockIdx.x * 64;
  const bool bf = (*flag != 0);
  for (int v = tid; v < 1024; v += 256){   // 8-elem chunks
    int row = v >> 4, c8 = v & 15;
    int node = base + row; if (node >= N_NODES) node = N_NODES - 1;
    size_t g = (size_t)node * 128 + c8 * 8;
    ushort8 u;
    if (bf){
      u = *(const ushort8*)((const unsigned short*)xin_ + g);
    } else {
      const float* xf = (const float*)xin_ + g;
      float4 f0 = *(const float4*)xf, f1 = *(const float4*)(xf + 4);
      u[0]=f2bf(f0.x); u[1]=f2bf(f0.y); u[2]=f2bf(f0.z); u[3]=f2bf(f0.w);
      u[4]=f2bf(f1.x); u[5]=f2bf(f1.y); u[6]=f2bf(f1.z); u[7]=f2bf(f1.w);
    }
    *(ushort8*)&xs[row * 136 + c8 * 8] = u;
  }
  __syncthreads();

  const int wave = tid >> 6, l = tid & 63;
  const int quad = l >> 4, m = l & 15;
  const int wbase = base + wave * 16;

  short8 afrag[4];
  #pragma unroll
  for (int kt = 0; kt < 4; ++kt)
    afrag[kt] = *(const short8*)&xs[(wave * 16 + m) * 136 + kt * 32 + quad * 8];

  f32x4 acc[16];
  #pragma unroll
  for (int nt = 0; nt < 16; ++nt) acc[nt] = (f32x4)0.f;

  #pragma unroll
  for (int nt = 0; nt < 16; ++nt){
    #pragma unroll
    for (int kt = 0; kt < 4; ++kt){
      short8 bfrag = *(const short8*)(Wb + ((size_t)(nt * 4 + kt) * 64 + l) * 8);
      acc[nt] = __builtin_amdgcn_mfma_f32_16x16x32_bf16(afrag[kt], bfrag, acc[nt], 0, 0, 0);
    }
  }
  // C/D: col = nt*16 + m, node = wbase + quad*4 + r
  #pragma unroll
  for (int r = 0; r < 4; ++r){
    int node = wbase + quad * 4 + r;
    if (node < N_NODES){
      #pragma unroll
      for (int nt = 0; nt < 16; ++nt)
        hmat[(size_t)node * 256 + nt * 16 + m] = (_Float16)acc[nt][r];
    }
  }

  // alphas: lane l -> h = l&3, seg = l>>2 (16 segments of 8 k)
  const int h = l & 3, seg = l >> 2;
  for (int nd = 0; nd < 16; ++nd){
    const unsigned short* xr = &xs[(wave * 16 + nd) * 136];
    float s_ = 0.f, d_ = 0.f;
    #pragma unroll
    for (int kk = 0; kk < 8; ++kk){
      int k = seg * 8 + kk;
      float xv = bf2f(xr[k]);
      s_ += xv * Bs[k * 4 + h];
      d_ += xv * Bd[k * 4 + h];
    }
    s_ += __shfl_xor(s_, 4);  s_ += __shfl_xor(s_, 8);
    s_ += __shfl_xor(s_, 16); s_ += __shfl_xor(s_, 32);
    d_ += __shfl_xor(d_, 4);  d_ += __shfl_xor(d_, 8);
    d_ += __shfl_xor(d_, 16); d_ += __shfl_xor(d_, 32);
    int n = wbase + nd;
    if (l < 4 && n < N_NODES){
      alpha_s[n * 4 + l] = s_;
      alpha_d[n * 4 + l] = d_;
    }
  }
}

// ---------------- layer-2 node transform (fp32 vector) ----------------

template<int F>
__global__ __launch_bounds__(256) void k_node(const float* __restrict__ xin,
    const float* __restrict__ Wc, const float* __restrict__ Bs, const float* __restrict__ Bd,
    _Float16* __restrict__ hmat, float* __restrict__ alpha_s, float* __restrict__ alpha_d)
{
  __shared__ float xs[32][F];
  const int tid = threadIdx.x;
  const int base = blockIdx.x * 32;
  const int nvec = 32 * F / 4;
  for (int v = tid; v < nvec; v += 256){
    size_t gf = (size_t)base * F + (size_t)v * 4;
    size_t gmax = (size_t)N_NODES * F - 4;
    if (gf > gmax) gf = gmax;
    *(float4*)&xs[0][v * 4] = *(const float4*)(xin + gf);
  }
  __syncthreads();

  const int wave = tid >> 6, l = tid & 63;
  const float* xw = &xs[wave * 8][0];
  float4 acc[8];
  #pragma unroll
  for (int nd = 0; nd < 8; ++nd) acc[nd] = make_float4(0.f,0.f,0.f,0.f);

  for (int kk = 0; kk < F; kk += 4){
    float xv[8][4];
    #pragma unroll
    for (int nd = 0; nd < 8; ++nd)
      *(float4*)xv[nd] = *(const float4*)(xw + nd * F + kk);
    #pragma unroll
    for (int j = 0; j < 4; ++j){
      float4 wv = *(const float4*)(Wc + (kk + j) * 256 + l * 4);
      #pragma unroll
      for (int nd = 0; nd < 8; ++nd){
        float xj = xv[nd][j];
        acc[nd].x += xj * wv.x; acc[nd].y += xj * wv.y;
        acc[nd].z += xj * wv.z; acc[nd].w += xj * wv.w;
      }
    }
  }
  #pragma unroll
  for (int nd = 0; nd < 8; ++nd){
    int n = base + wave * 8 + nd;
    if (n < N_NODES){
      half4 o;
      o.x = (_Float16)acc[nd].x; o.y = (_Float16)acc[nd].y;
      o.z = (_Float16)acc[nd].z; o.w = (_Float16)acc[nd].w;
      *(half4*)(hmat + (size_t)n * 256 + l * 4) = o;
    }
  }

  const int h = l & 3, seg = l >> 2;
  const int KS = F / 16;
  for (int nd = 0; nd < 8; ++nd){
    const float* xr = xw + nd * F;
    float s_ = 0.f, d_ = 0.f;
    #pragma unroll
    for (int kk = 0; kk < KS; ++kk){
      int k = seg * KS + kk;
      float xv_ = xr[k];
      s_ += xv_ * Bs[k * 4 + h];
      d_ += xv_ * Bd[k * 4 + h];
    }
    s_ += __shfl_xor(s_, 4);  s_ += __shfl_xor(s_, 8);
    s_ += __shfl_xor(s_, 16); s_ += __shfl_xor(s_, 32);
    d_ += __shfl_xor(d_, 4);  d_ += __shfl_xor(d_, 8);
    d_ += __shfl_xor(d_, 16); d_ += __shfl_xor(d_, 32);
    int n = base + wave * 8 + nd;
    if (l < 4 && n < N_NODES){
      alpha_s[n * 4 + l] = s_;
      alpha_d[n * 4 + l] = d_;
    }
  }
}

// ---------------- aggregation: edge softmax + weighted sum per dst ----------------

template<bool FINAL>
__global__ __launch_bounds__(256) void k_aggr(
    const _Float16* __restrict__ hmat, const float* __restrict__ alpha_s,
    const float* __restrict__ alpha_d, const int* __restrict__ rowptr,
    const int* __restrict__ csr_src, const float* __restrict__ bias,
    void* __restrict__ out, const int* __restrict__ flag)
{
  const int tid = threadIdx.x;
  const int wave = tid >> 6, l = tid & 63;
  const int n = blockIdx.x * 4 + wave;
  const int hh = l >> 4;
  const float adv = alpha_d[n * 4 + hh];
  const int p0 = rowptr[n], p1 = rowptr[n + 1];
  float4 acc = make_float4(0.f,0.f,0.f,0.f);
  float den = 0.f;
  int p = p0;
  for (; p + 4 <= p1; p += 4){
    int s0 = csr_src[p],     s1 = csr_src[p + 1];
    int s2 = csr_src[p + 2], s3 = csr_src[p + 3];
    float a0 = alpha_s[s0 * 4 + hh], a1 = alpha_s[s1 * 4 + hh];
    float a2 = alpha_s[s2 * 4 + hh], a3 = alpha_s[s3 * 4 + hh];
    half4 h0 = *(const half4*)(hmat + (size_t)s0 * 256 + l * 4);
    half4 h1 = *(const half4*)(hmat + (size_t)s1 * 256 + l * 4);
    half4 h2 = *(const half4*)(hmat + (size_t)s2 * 256 + l * 4);
    half4 h3 = *(const half4*)(hmat + (size_t)s3 * 256 + l * 4);
    float e0 = a0 + adv; e0 = (e0 >= 0.f) ? e0 : 0.2f * e0;
    float e1 = a1 + adv; e1 = (e1 >= 0.f) ? e1 : 0.2f * e1;
    float e2 = a2 + adv; e2 = (e2 >= 0.f) ? e2 : 0.2f * e2;
    float e3 = a3 + adv; e3 = (e3 >= 0.f) ? e3 : 0.2f * e3;
    float ex0 = __expf(e0), ex1 = __expf(e1), ex2 = __expf(e2), ex3 = __expf(e3);
    den += (ex0 + ex1) + (ex2 + ex3);
    acc.x += ex0 * (float)h0.x + ex1 * (float)h1.x + ex2 * (float)h2.x + ex3 * (float)h3.x;
    acc.y += ex0 * (float)h0.y + ex1 * (float)h1.y + ex2 * (float)h2.y + ex3 * (float)h3.y;
    acc.z += ex0 * (float)h0.z + ex1 * (float)h1.z + ex2 * (float)h2.z + ex3 * (float)h3.z;
    acc.w += ex0 * (float)h0.w + ex1 * (float)h1.w + ex2 * (float)h2.w + ex3 * (float)h3.w;
  }
  for (; p < p1; ++p){
    int s = csr_src[p];
    float e = alpha_s[s * 4 + hh] + adv;
    e = (e >= 0.f) ? e : 0.2f * e;
    float ex = __expf(e);
    half4 hv = *(const half4*)(hmat + (size_t)s * 256 + l * 4);
    den += ex;
    acc.x += ex * (float)hv.x; acc.y += ex * (float)hv.y;
    acc.z += ex * (float)hv.z; acc.w += ex * (float)hv.w;
  }
  float r = (den > 0.f) ? (1.f / den) : 0.f;
  acc.x *= r; acc.y *= r; acc.z *= r; acc.w *= r;
  acc.x += __shfl_xor(acc.x, 16); acc.y += __shfl_xor(acc.y, 16);
  acc.z += __shfl_xor(acc.z, 16); acc.w += __shfl_xor(acc.w, 16);
  acc.x += __shfl_xor(acc.x, 32); acc.y += __shfl_xor(acc.y, 32);
  acc.z += __shfl_xor(acc.z, 32); acc.w += __shfl_xor(acc.w, 32);
  if (l < 16){
    float vx = 0.25f * acc.x + bias[l * 4 + 0];
    float vy = 0.25f * acc.y + bias[l * 4 + 1];
    float vz = 0.25f * acc.z + bias[l * 4 + 2];
    float vw = 0.25f * acc.w + bias[l * 4 + 3];
    vx = (vx >= 0.f) ? vx : 0.1f * vx;
    vy = (vy >= 0.f) ? vy : 0.1f * vy;
    vz = (vz >= 0.f) ? vz : 0.1f * vz;
    vw = (vw >= 0.f) ? vw : 0.1f * vw;
    bool bf16out = false;
    if (FINAL) bf16out = (*flag != 0);
    if (FINAL && bf16out){
      ushort4 o = make_ushort4(f2bf(vx), f2bf(vy), f2bf(vz), f2bf(vw));
      *(ushort4*)((unsigned short*)out + (size_t)n * 64 + l * 4) = o;
    } else {
      *(float4*)((float*)out + (size_t)n * 64 + l * 4) = make_float4(vx, vy, vz, vw);
    }
  }
}

// ---------------- launch ----------------

extern "C" void kernel_launch(void* const* d_in, const int* in_sizes, int n_in,
                              void* d_out, int out_size, void* d_ws, size_t ws_size,
                              hipStream_t stream)
{
  const void* x  = d_in[0];
  const int* ei  = (const int*)d_in[1];
  const int* src = ei;
  const int* dst = ei + N_EDGES;

  char* ws = (char*)d_ws;                      // footprint ~69.6 MB
  _Float16* hmat = (_Float16*)(ws);            // [N,256] fp16 (25.6 MB)
  unsigned short* Wb1 = (unsigned short*)(ws + 25600000);  // [32768] bf16 swizzled W1
  float* x2     = (float*)(ws + 51200000);     // [N,64]  f32 layer-1 output
  float* as_    = (float*)(ws + 64000000);     // [N,4]
  float* ad_    = (float*)(ws + 64800000);     // [N,4]
  int*   deg    = (int*)  (ws + 65600000);     // [N]
  int*   fill   = (int*)  (ws + 65800000);     // [N]
  int*   rowptr = (int*)  (ws + 66000000);     // [N+1]
  int*   csr    = (int*)  (ws + 66200064);     // [E] src sorted by dst
  int*   flag   = (int*)  (ws + 69400064);     // dtype flag (1 = bf16)
  float* Ac1    = (float*)(ws + 69531200);     // [128*16]
  float* aSc1   = (float*)(ws + 69539392);     // [16]
  float* aDc1   = (float*)(ws + 69539456);     // [16]
  float* bc1    = (float*)(ws + 69539520);     // [64]
  float* Wc2    = (float*)(ws + 69539776);     // [64*256]
  float* Ac2    = (float*)(ws + 69605312);     // [64*16]
  float* aSc2   = (float*)(ws + 69609408);     // [16]
  float* aDc2   = (float*)(ws + 69609472);     // [16]
  float* bc2    = (float*)(ws + 69609536);     // [64]
  int*   bsum   = (int*)  (ws + 69609792);     // [256]
  int*   boff   = (int*)  (ws + 69610816);     // [256]
  float* Bs1    = (float*)(ws + 69611840);     // [128*4]
  float* Bd1    = (float*)(ws + 69613888);     // [128*4]
  float* Bs2    = (float*)(ws + 69615936);     // [64*4]
  float* Bd2    = (float*)(ws + 69616960);     // [64*4]

  k_detect<<<1, 64, 0, stream>>>((const unsigned int*)x, flag);

  ParamPtrs P;
  P.src[0] = d_in[3];  P.dst[0] = Ac1;  P.len[0] = 128 * 16;
  P.src[1] = d_in[4];  P.dst[1] = aSc1; P.len[1] = 16;
  P.src[2] = d_in[5];  P.dst[2] = aDc1; P.len[2] = 16;
  P.src[3] = d_in[6];  P.dst[3] = bc1;  P.len[3] = 64;
  P.src[4] = d_in[7];  P.dst[4] = Wc2;  P.len[4] = 64 * 256;
  P.src[5] = d_in[8];  P.dst[5] = Ac2;  P.len[5] = 64 * 16;
  P.src[6] = d_in[9];  P.dst[6] = aSc2; P.len[6] = 16;
  P.src[7] = d_in[10]; P.dst[7] = aDc2; P.len[7] = 16;
  P.src[8] = d_in[11]; P.dst[8] = bc2;  P.len[8] = 64;
  P.src[9] = d_in[11]; P.dst[9] = bc2;  P.len[9] = 0;
  k_params<<<dim3(64, 9), 256, 0, stream>>>(P, flag);
  k_wswz  <<<128, 256, 0, stream>>>(d_in[2], Wb1, flag);
  k_prep  <<<3, 256, 0, stream>>>(Ac1, aSc1, aDc1, Bs1, Bd1, Ac2, aSc2, aDc2, Bs2, Bd2);

  k_zero   <<<NB_SCAN, 256, 0, stream>>>(deg, fill);
  k_hist   <<<(N_EDGES + 255) / 256, 256, 0, stream>>>(dst, deg);
  k_scan1  <<<NB_SCAN, 256, 0, stream>>>(deg, bsum);
  k_scan2  <<<1, 256, 0, stream>>>(bsum, boff);
  k_scan3  <<<NB_SCAN, 256, 0, stream>>>(deg, boff, rowptr);
  k_scatter<<<(N_EDGES + 255) / 256, 256, 0, stream>>>(src, dst, rowptr, fill, csr);

  // layer 1 (Fin=128, bf16 MFMA)
  k_node1<<<(N_NODES + 63) / 64, 256, 0, stream>>>(x, Wb1, Bs1, Bd1, hmat, as_, ad_, flag);
  k_aggr<false><<<N_NODES / 4, 256, 0, stream>>>(hmat, as_, ad_, rowptr, csr, bc1, x2, flag);
  // layer 2 (Fin=64, f32 vector)
  k_node<64><<<(N_NODES + 31) / 32, 256, 0, stream>>>(x2, Wc2, Bs2, Bd2, hmat, as_, ad_);
  k_aggr<true><<<N_NODES / 4, 256, 0, stream>>>(hmat, as_, ad_, rowptr, csr, bc2, d_out, flag);
}

// Round 10
// 352.576 us; speedup vs baseline: 1.9097x; 1.0294x over previous
//
#include <hip/hip_runtime.h>

// GAT 2-layer fused pipeline for MI355X.
// N=50000 nodes, E=800000 edges, H=4 heads, C=64 channels, D=4 att dims.
// Inputs bf16 (runtime-detected, fp32 fallback); edge_index int32.
// Internal: bf16 MFMA node transforms, fp16 h matrix, fp32 accumulation.
//
// Round-10 changes vs round-9 (passed 362.9 us; k_aggr x2 at 63.6 us each,
// VALUBusy 67% + fabric 42%):
//  - layer-2 node -> MFMA (k_nodeM<64>); x2 stored bf16 by k_aggr<0>.
//  - k_aggr: int4 csr loads, 32-bit byte-offset addressing, max-form leaky.
//  - setup kernels fused into one k_setup (prep reads raw inputs directly).

#define N_NODES 50000
#define N_EDGES 800000
#define NB_SCAN 196   // ceil(N_NODES/256)

typedef _Float16 half4 __attribute__((ext_vector_type(4)));
typedef __attribute__((ext_vector_type(8))) short short8;     // 8 bf16
typedef __attribute__((ext_vector_type(4))) float f32x4;
typedef __attribute__((ext_vector_type(8))) unsigned short ushort8;

__device__ __forceinline__ float bf2f(unsigned short u){
  return __uint_as_float(((unsigned int)u) << 16);
}
__device__ __forceinline__ unsigned short f2bf(float f){
  unsigned int u = __float_as_uint(f);
  u = (u + 0x7FFFu + ((u >> 16) & 1u)) >> 16;   // round-to-nearest-even
  return (unsigned short)u;
}
__device__ __forceinline__ float ldf(const void* p, int i, bool bf){
  return bf ? bf2f(((const unsigned short*)p)[i]) : ((const float*)p)[i];
}

// ---------------- dtype probe ----------------
__global__ void k_detect(const unsigned int* __restrict__ xb, int* __restrict__ flag){
  int l = threadIdx.x;
  unsigned int w = xb[l] & 0xFFFFu;
  unsigned int e = (w >> 7) & 0xFFu;
  bool hit = (e >= 100u && e <= 135u);
  unsigned long long m = __ballot(hit);
  if (l == 0) *flag = (__popcll(m) > 40) ? 1 : 0;   // 1 = bf16 inputs
}

// ---------------- fused setup: zero + W swizzles + Bs/Bd prep + bias ----------------
// W[FxN=256] -> bf16 B-fragment layout for mfma_f32_16x16x32_bf16:
// Wb[((nt*KT + kt)*64 + lane)*8 + j] = W[k = kt*32 + (lane>>4)*8 + j][n = nt*16 + (lane&15)]
struct SetupPtrs {
  const void *W1, *A1, *aS1, *aD1, *b1, *W2, *A2, *aS2, *aD2, *b2;
};

__global__ __launch_bounds__(256) void k_setup(SetupPtrs S,
    int* __restrict__ deg, int* __restrict__ fill,
    unsigned short* __restrict__ Wb1, unsigned short* __restrict__ Wb2,
    float* __restrict__ Bs1, float* __restrict__ Bd1,
    float* __restrict__ Bs2, float* __restrict__ Bd2,
    float* __restrict__ bc1, float* __restrict__ bc2,
    const int* __restrict__ flag)
{
  const bool bf = (*flag != 0);
  const int b = blockIdx.x, tid = threadIdx.x;
  if (b < 196){                                   // zero deg/fill
    int i = b * 256 + tid;
    if (i < N_NODES){ deg[i] = 0; fill[i] = 0; }
  } else if (b < 324){                            // wswz W1 (F=128, KT=4): 32768 elems
    int t = (b - 196) * 256 + tid;
    int j = t & 7, lane = (t >> 3) & 63, kt = (t >> 9) & 3, nt = t >> 11;
    int k = kt * 32 + (lane >> 4) * 8 + j;
    int n = nt * 16 + (lane & 15);
    Wb1[t] = bf ? ((const unsigned short*)S.W1)[k * 256 + n]
                : f2bf(((const float*)S.W1)[k * 256 + n]);
  } else if (b < 388){                            // wswz W2 (F=64, KT=2): 16384 elems
    int t = (b - 324) * 256 + tid;
    int j = t & 7, lane = (t >> 3) & 63, kt = (t >> 9) & 1, nt = t >> 10;
    int k = kt * 32 + (lane >> 4) * 8 + j;
    int n = nt * 16 + (lane & 15);
    Wb2[t] = bf ? ((const unsigned short*)S.W2)[k * 256 + n]
                : f2bf(((const float*)S.W2)[k * 256 + n]);
  } else if (b < 391){                            // Bs/Bd prep: 768 items
    int t = (b - 388) * 256 + tid;
    if (t < 512){
      int k = t >> 2, h = t & 3;
      float s = 0.f, d = 0.f;
      for (int dd = 0; dd < 4; ++dd){
        float av = ldf(S.A1, k * 16 + h * 4 + dd, bf);
        s += av * ldf(S.aS1, h * 4 + dd, bf);
        d += av * ldf(S.aD1, h * 4 + dd, bf);
      }
      Bs1[t] = s; Bd1[t] = d;
    } else if (t < 768){
      int u = t - 512, k = u >> 2, h = u & 3;
      float s = 0.f, d = 0.f;
      for (int dd = 0; dd < 4; ++dd){
        float av = ldf(S.A2, k * 16 + h * 4 + dd, bf);
        s += av * ldf(S.aS2, h * 4 + dd, bf);
        d += av * ldf(S.aD2, h * 4 + dd, bf);
      }
      Bs2[u] = s; Bd2[u] = d;
    }
  } else {                                        // bias copies
    if (tid < 64)       bc1[tid] = ldf(S.b1, tid, bf);
    else if (tid < 128) bc2[tid - 64] = ldf(S.b2, tid - 64, bf);
  }
}

// ---------------- CSR build ----------------

__global__ __launch_bounds__(256) void k_hist(const int* __restrict__ dst,
                                              int* __restrict__ deg){
  int e = blockIdx.x * 256 + threadIdx.x;
  if (e < N_EDGES) atomicAdd(&deg[dst[e]], 1);
}

__global__ __launch_bounds__(256) void k_scan1(const int* __restrict__ deg,
                                               int* __restrict__ blocksum){
  int b = blockIdx.x, t = threadIdx.x, i = b * 256 + t;
  int v = (i < N_NODES) ? deg[i] : 0;
  for (int off = 1; off < 64; off <<= 1) v += __shfl_xor(v, off);
  __shared__ int sm[4];
  if ((t & 63) == 0) sm[t >> 6] = v;
  __syncthreads();
  if (t == 0) blocksum[b] = sm[0] + sm[1] + sm[2] + sm[3];
}

__global__ __launch_bounds__(256) void k_scan2(const int* __restrict__ blocksum,
                                               int* __restrict__ blockoff){
  __shared__ int sm[256];
  int t = threadIdx.x;
  int v = (t < NB_SCAN) ? blocksum[t] : 0;
  sm[t] = v;
  __syncthreads();
  for (int off = 1; off < 256; off <<= 1){
    int u = (t >= off) ? sm[t - off] : 0;
    __syncthreads();
    sm[t] += u;
    __syncthreads();
  }
  blockoff[t] = sm[t] - v;   // exclusive
}

__global__ __launch_bounds__(256) void k_scan3(const int* __restrict__ deg,
                                               const int* __restrict__ blockoff,
                                               int* __restrict__ rowptr){
  __shared__ int sm[256];
  int b = blockIdx.x, t = threadIdx.x, i = b * 256 + t;
  int v = (i < N_NODES) ? deg[i] : 0;
  sm[t] = v;
  __syncthreads();
  for (int off = 1; off < 256; off <<= 1){
    int u = (t >= off) ? sm[t - off] : 0;
    __syncthreads();
    sm[t] += u;
    __syncthreads();
  }
  if (i < N_NODES) rowptr[i] = blockoff[b] + sm[t] - v;
  if (i == 0) rowptr[N_NODES] = N_EDGES;
}

__global__ __launch_bounds__(256) void k_scatter(const int* __restrict__ src,
                                                 const int* __restrict__ dst,
                                                 const int* __restrict__ rowptr,
                                                 int* __restrict__ fill,
                                                 int* __restrict__ csr_src){
  int e = blockIdx.x * 256 + threadIdx.x;
  if (e < N_EDGES){
    int d = dst[e];
    int pos = rowptr[d] + atomicAdd(&fill[d], 1);
    csr_src[pos] = src[e];
  }
}

// ---------------- node transform via MFMA (F = 128 or 64) ----------------
// block = 256 = 4 waves, 16 nodes/wave (64/block). h = x@W via
// mfma_f32_16x16x32_bf16 (fp32 accum), fp16 store. Alphas fp32 vector path.
// DYN: input dtype from flag (layer 1). !DYN: input is bf16 (internal x2).

template<int F, bool DYN>
__global__ __launch_bounds__(256) void k_nodeM(const void* __restrict__ xin_,
    const unsigned short* __restrict__ Wb,
    const float* __restrict__ Bs, const float* __restrict__ Bd,
    _Float16* __restrict__ hmat, float* __restrict__ alpha_s, float* __restrict__ alpha_d,
    const int* __restrict__ flag)
{
  const int STR = F + 8;                   // row stride in ushorts (16B pad, 16B-aligned)
  const int KT  = F / 32;                  // K-tiles of 32
  const int CH  = F / 8;                   // ushort8 chunks per row
  __shared__ unsigned short xs[64 * (F + 8)];
  const int tid = threadIdx.x;
  const int base = blockIdx.x * 64;
  bool bf = true;
  if (DYN) bf = (*flag != 0);
  for (int v = tid; v < 64 * CH; v += 256){
    int row = v / CH, c8 = v % CH;
    int node = base + row; if (node >= N_NODES) node = N_NODES - 1;
    size_t g = (size_t)node * F + c8 * 8;
    ushort8 u;
    if (!DYN || bf){
      u = *(const ushort8*)((const unsigned short*)xin_ + g);
    } else {
      const float* xf = (const float*)xin_ + g;
      float4 f0 = *(const float4*)xf, f1 = *(const float4*)(xf + 4);
      u[0]=f2bf(f0.x); u[1]=f2bf(f0.y); u[2]=f2bf(f0.z); u[3]=f2bf(f0.w);
      u[4]=f2bf(f1.x); u[5]=f2bf(f1.y); u[6]=f2bf(f1.z); u[7]=f2bf(f1.w);
    }
    *(ushort8*)&xs[row * STR + c8 * 8] = u;
  }
  __syncthreads();

  const int wave = tid >> 6, l = tid & 63;
  const int quad = l >> 4, m = l & 15;
  const int wbase = base + wave * 16;

  short8 afrag[KT];
  #pragma unroll
  for (int kt = 0; kt < KT; ++kt)
    afrag[kt] = *(const short8*)&xs[(wave * 16 + m) * STR + kt * 32 + quad * 8];

  f32x4 acc[16];
  #pragma unroll
  for (int nt = 0; nt < 16; ++nt) acc[nt] = (f32x4)0.f;

  #pragma unroll
  for (int nt = 0; nt < 16; ++nt){
    #pragma unroll
    for (int kt = 0; kt < KT; ++kt){
      short8 bfrag = *(const short8*)(Wb + ((size_t)(nt * KT + kt) * 64 + l) * 8);
      acc[nt] = __builtin_amdgcn_mfma_f32_16x16x32_bf16(afrag[kt], bfrag, acc[nt], 0, 0, 0);
    }
  }
  // C/D: col = nt*16 + m, node = wbase + quad*4 + r
  #pragma unroll
  for (int r = 0; r < 4; ++r){
    int node = wbase + quad * 4 + r;
    if (node < N_NODES){
      #pragma unroll
      for (int nt = 0; nt < 16; ++nt)
        hmat[(size_t)node * 256 + nt * 16 + m] = (_Float16)acc[nt][r];
    }
  }

  // alphas: lane l -> h = l&3, seg = l>>2 (16 segments of F/16 k)
  const int h = l & 3, seg = l >> 2;
  const int KS = F / 16;
  for (int nd = 0; nd < 16; ++nd){
    const unsigned short* xr = &xs[(wave * 16 + nd) * STR];
    float s_ = 0.f, d_ = 0.f;
    #pragma unroll
    for (int kk = 0; kk < KS; ++kk){
      int k = seg * KS + kk;
      float xv = bf2f(xr[k]);
      s_ += xv * Bs[k * 4 + h];
      d_ += xv * Bd[k * 4 + h];
    }
    s_ += __shfl_xor(s_, 4);  s_ += __shfl_xor(s_, 8);
    s_ += __shfl_xor(s_, 16); s_ += __shfl_xor(s_, 32);
    d_ += __shfl_xor(d_, 4);  d_ += __shfl_xor(d_, 8);
    d_ += __shfl_xor(d_, 16); d_ += __shfl_xor(d_, 32);
    int n = wbase + nd;
    if (l < 4 && n < N_NODES){
      alpha_s[n * 4 + l] = s_;
      alpha_d[n * 4 + l] = d_;
    }
  }
}

// ---------------- aggregation: edge softmax + weighted sum per dst ----------------
// block = 256 = 4 waves, one wave per dst node. Lane l: head hh=l>>4, 4 channels.
// MODE 0: write x2 bf16 (internal). MODE 1: final output (flag: bf16 else fp32).

template<int MODE>
__global__ __launch_bounds__(256) void k_aggr(
    const _Float16* __restrict__ hmat, const float* __restrict__ alpha_s,
    const float* __restrict__ alpha_d, const int* __restrict__ rowptr,
    const int* __restrict__ csr_src, const float* __restrict__ bias,
    void* __restrict__ out, const int* __restrict__ flag)
{
  const int tid = threadIdx.x;
  const int wave = tid >> 6, l = tid & 63;
  const int n = blockIdx.x * 4 + wave;
  const int hh = l >> 4;
  const float adv = alpha_d[n * 4 + hh];
  const int p0 = rowptr[n], p1 = rowptr[n + 1];
  const char* hb = (const char*)hmat + l * 8;          // lane base, 8B per half4
  const char* ab = (const char*)alpha_s + hh * 4;      // head base, 16B per node
  float4 acc = make_float4(0.f,0.f,0.f,0.f);
  float den = 0.f;
  int p = p0;
  int pa = (p0 + 3) & ~3; if (pa > p1) pa = p1;
  for (; p < pa; ++p){                                 // head to 16B alignment
    int s = csr_src[p];
    float e = *(const float*)(ab + ((unsigned)s << 4)) + adv;
    e = fmaxf(e, 0.2f * e);
    float ex = __expf(e);
    half4 hv = *(const half4*)(hb + ((unsigned)s << 9));
    den += ex;
    acc.x += ex * (float)hv.x; acc.y += ex * (float)hv.y;
    acc.z += ex * (float)hv.z; acc.w += ex * (float)hv.w;
  }
  for (; p + 4 <= p1; p += 4){
    int4 s4 = *(const int4*)(csr_src + p);             // aligned 16B
    float a0 = *(const float*)(ab + ((unsigned)s4.x << 4));
    float a1 = *(const float*)(ab + ((unsigned)s4.y << 4));
    float a2 = *(const float*)(ab + ((unsigned)s4.z << 4));
    float a3 = *(const float*)(ab + ((unsigned)s4.w << 4));
    half4 h0 = *(const half4*)(hb + ((unsigned)s4.x << 9));
    half4 h1 = *(const half4*)(hb + ((unsigned)s4.y << 9));
    half4 h2 = *(const half4*)(hb + ((unsigned)s4.z << 9));
    half4 h3 = *(const half4*)(hb + ((unsigned)s4.w << 9));
    float e0 = a0 + adv; e0 = fmaxf(e0, 0.2f * e0);
    float e1 = a1 + adv; e1 = fmaxf(e1, 0.2f * e1);
    float e2 = a2 + adv; e2 = fmaxf(e2, 0.2f * e2);
    float e3 = a3 + adv; e3 = fmaxf(e3, 0.2f * e3);
    float ex0 = __expf(e0), ex1 = __expf(e1), ex2 = __expf(e2), ex3 = __expf(e3);
    den += (ex0 + ex1) + (ex2 + ex3);
    acc.x += ex0 * (float)h0.x + ex1 * (float)h1.x + ex2 * (float)h2.x + ex3 * (float)h3.x;
    acc.y += ex0 * (float)h0.y + ex1 * (float)h1.y + ex2 * (float)h2.y + ex3 * (float)h3.y;
    acc.z += ex0 * (float)h0.z + ex1 * (float)h1.z + ex2 * (float)h2.z + ex3 * (float)h3.z;
    acc.w += ex0 * (float)h0.w + ex1 * (float)h1.w + ex2 * (float)h2.w + ex3 * (float)h3.w;
  }
  for (; p < p1; ++p){                                 // tail
    int s = csr_src[p];
    float e = *(const float*)(ab + ((unsigned)s << 4)) + adv;
    e = fmaxf(e, 0.2f * e);
    float ex = __expf(e);
    half4 hv = *(const half4*)(hb + ((unsigned)s << 9));
    den += ex;
    acc.x += ex * (float)hv.x; acc.y += ex * (float)hv.y;
    acc.z += ex * (float)hv.z; acc.w += ex * (float)hv.w;
  }
  float r = (den > 0.f) ? (1.f / den) : 0.f;
  acc.x *= r; acc.y *= r; acc.z *= r; acc.w *= r;
  acc.x += __shfl_xor(acc.x, 16); acc.y += __shfl_xor(acc.y, 16);
  acc.z += __shfl_xor(acc.z, 16); acc.w += __shfl_xor(acc.w, 16);
  acc.x += __shfl_xor(acc.x, 32); acc.y += __shfl_xor(acc.y, 32);
  acc.z += __shfl_xor(acc.z, 32); acc.w += __shfl_xor(acc.w, 32);
  if (l < 16){
    float vx = 0.25f * acc.x + bias[l * 4 + 0];
    float vy = 0.25f * acc.y + bias[l * 4 + 1];
    float vz = 0.25f * acc.z + bias[l * 4 + 2];
    float vw = 0.25f * acc.w + bias[l * 4 + 3];
    vx = fmaxf(vx, 0.1f * vx);                          // post-layer leaky 0.1
    vy = fmaxf(vy, 0.1f * vy);
    vz = fmaxf(vz, 0.1f * vz);
    vw = fmaxf(vw, 0.1f * vw);
    if (MODE == 0){
      ushort4 o = make_ushort4(f2bf(vx), f2bf(vy), f2bf(vz), f2bf(vw));
      *(ushort4*)((unsigned short*)out + (size_t)n * 64 + l * 4) = o;   // x2 bf16
    } else {
      if (*flag){
        ushort4 o = make_ushort4(f2bf(vx), f2bf(vy), f2bf(vz), f2bf(vw));
        *(ushort4*)((unsigned short*)out + (size_t)n * 64 + l * 4) = o;
      } else {
        *(float4*)((float*)out + (size_t)n * 64 + l * 4) = make_float4(vx, vy, vz, vw);
      }
    }
  }
}

// ---------------- launch ----------------

extern "C" void kernel_launch(void* const* d_in, const int* in_sizes, int n_in,
                              void* d_out, int out_size, void* d_ws, size_t ws_size,
                              hipStream_t stream)
{
  const void* x  = d_in[0];
  const int* ei  = (const int*)d_in[1];
  const int* src = ei;
  const int* dst = ei + N_EDGES;

  char* ws = (char*)d_ws;                      // footprint ~69.7 MB
  _Float16* hmat = (_Float16*)(ws);            // [N,256] fp16 (25.6 MB)
  unsigned short* Wb1 = (unsigned short*)(ws + 25600000);  // [32768] bf16 swizzled W1
  unsigned short* Wb2 = (unsigned short*)(ws + 25665536);  // [16384] bf16 swizzled W2
  unsigned short* x2  = (unsigned short*)(ws + 51200000);  // [N,64] bf16 layer-1 output
  float* as_    = (float*)(ws + 64000000);     // [N,4]
  float* ad_    = (float*)(ws + 64800000);     // [N,4]
  int*   deg    = (int*)  (ws + 65600000);     // [N]
  int*   fill   = (int*)  (ws + 65800000);     // [N]
  int*   rowptr = (int*)  (ws + 66000000);     // [N+1]
  int*   csr    = (int*)  (ws + 66200064);     // [E] src sorted by dst, 16B-aligned
  int*   flag   = (int*)  (ws + 69400064);     // dtype flag (1 = bf16)
  float* bc1    = (float*)(ws + 69539520);     // [64]
  float* bc2    = (float*)(ws + 69609536);     // [64]
  int*   bsum   = (int*)  (ws + 69609792);     // [256]
  int*   boff   = (int*)  (ws + 69610816);     // [256]
  float* Bs1    = (float*)(ws + 69611840);     // [128*4]
  float* Bd1    = (float*)(ws + 69613888);     // [128*4]
  float* Bs2    = (float*)(ws + 69615936);     // [64*4]
  float* Bd2    = (float*)(ws + 69616960);     // [64*4]

  k_detect<<<1, 64, 0, stream>>>((const unsigned int*)x, flag);

  SetupPtrs S;
  S.W1 = d_in[2];  S.A1 = d_in[3];  S.aS1 = d_in[4];  S.aD1 = d_in[5];  S.b1 = d_in[6];
  S.W2 = d_in[7];  S.A2 = d_in[8];  S.aS2 = d_in[9];  S.aD2 = d_in[10]; S.b2 = d_in[11];
  k_setup<<<392, 256, 0, stream>>>(S, deg, fill, Wb1, Wb2,
                                   Bs1, Bd1, Bs2, Bd2, bc1, bc2, flag);

  k_hist   <<<(N_EDGES + 255) / 256, 256, 0, stream>>>(dst, deg);
  k_scan1  <<<NB_SCAN, 256, 0, stream>>>(deg, bsum);
  k_scan2  <<<1, 256, 0, stream>>>(bsum, boff);
  k_scan3  <<<NB_SCAN, 256, 0, stream>>>(deg, boff, rowptr);
  k_scatter<<<(N_EDGES + 255) / 256, 256, 0, stream>>>(src, dst, rowptr, fill, csr);

  // layer 1 (Fin=128, dtype per flag)
  k_nodeM<128, true><<<(N_NODES + 63) / 64, 256, 0, stream>>>(x, Wb1, Bs1, Bd1, hmat, as_, ad_, flag);
  k_aggr<0><<<N_NODES / 4, 256, 0, stream>>>(hmat, as_, ad_, rowptr, csr, bc1, x2, flag);
  // layer 2 (Fin=64, bf16 internal)
  k_nodeM<64, false><<<(N_NODES + 63) / 64, 256, 0, stream>>>(x2, Wb2, Bs2, Bd2, hmat, as_, ad_, flag);
  k_aggr<1><<<N_NODES / 4, 256, 0, stream>>>(hmat, as_, ad_, rowptr, csr, bc2, d_out, flag);
}

// Round 12
// 336.256 us; speedup vs baseline: 2.0024x; 1.0485x over previous
//
#include <hip/hip_runtime.h>

// GAT 2-layer fused pipeline for MI355X.
// N=50000 nodes, E=800000 edges, H=4 heads, C=64 channels, D=4 att dims.
// Inputs bf16 (runtime-detected, fp32 fallback); edge_index int32.
// Internal: bf16 MFMA node transforms, fp16 h matrix, fp32 accumulation.
//
// Round-12 vs round-10 (passed 352.6 us) / round-11 (FAILED post-timing:
// first launch correct, replays diverged; pos/hmat ws-alias + half-wave aggr
// were the novelties -> both REVERTED):
//  - k_aggr: exact r10 version (one wave per dst, 8B lanes, int4 csr loads).
//  - CSR build: r10 atomic-fill scatter (no ws aliasing anywhere).
//  - scan2+scan3 fused (kept: pure function of deg, no aliasing).
//  - NEW: alphas via MFMA — Bsd[k][c] (Bs|Bd|0) pre-swizzled bf16 B-fragments,
//    KT extra MFMAs reuse afrag; removes the ~640-op/lane scalar alpha tail.

#define N_NODES 50000
#define N_EDGES 800000
#define NB_SCAN 196   // ceil(N_NODES/256)

typedef _Float16 half4 __attribute__((ext_vector_type(4)));
typedef __attribute__((ext_vector_type(8))) short short8;     // 8 bf16
typedef __attribute__((ext_vector_type(4))) float f32x4;
typedef __attribute__((ext_vector_type(8))) unsigned short ushort8;

__device__ __forceinline__ float bf2f(unsigned short u){
  return __uint_as_float(((unsigned int)u) << 16);
}
__device__ __forceinline__ unsigned short f2bf(float f){
  unsigned int u = __float_as_uint(f);
  u = (u + 0x7FFFu + ((u >> 16) & 1u)) >> 16;   // round-to-nearest-even
  return (unsigned short)u;
}
__device__ __forceinline__ float ldf(const void* p, int i, bool bf){
  return bf ? bf2f(((const unsigned short*)p)[i]) : ((const float*)p)[i];
}

// ---------------- dtype probe ----------------
__global__ void k_detect(const unsigned int* __restrict__ xb, int* __restrict__ flag){
  int l = threadIdx.x;
  unsigned int w = xb[l] & 0xFFFFu;
  unsigned int e = (w >> 7) & 0xFFu;
  bool hit = (e >= 100u && e <= 135u);
  unsigned long long m = __ballot(hit);
  if (l == 0) *flag = (__popcll(m) > 40) ? 1 : 0;   // 1 = bf16 inputs
}

// ---------------- fused setup ----------------
// W[Fx256] -> bf16 B-fragment layout for mfma_f32_16x16x32_bf16:
// Wb[((nt*KT + kt)*64 + lane)*8 + j] = W[k = kt*32 + (lane>>4)*8 + j][n = nt*16 + (lane&15)]
// Bsd fragments: Bsdf[(kt*64 + lane)*8 + j] = Bsd[k][c=lane&15],
//   Bsd[k][c] = c<4 ? sum_d A[k,c*4+d]*attS[c*4+d]
//             : c<8 ? sum_d A[k,(c-4)*4+d]*attD[(c-4)*4+d] : 0
struct SetupPtrs {
  const void *W1, *A1, *aS1, *aD1, *b1, *W2, *A2, *aS2, *aD2, *b2;
};

__global__ __launch_bounds__(256) void k_setup(SetupPtrs S,
    int* __restrict__ deg, int* __restrict__ fill,
    unsigned short* __restrict__ Wb1, unsigned short* __restrict__ Wb2,
    unsigned short* __restrict__ Bsd1f, unsigned short* __restrict__ Bsd2f,
    float* __restrict__ bc1, float* __restrict__ bc2,
    const int* __restrict__ flag)
{
  const bool bf = (*flag != 0);
  const int b = blockIdx.x, tid = threadIdx.x;
  if (b < 196){                                   // zero deg/fill
    int i = b * 256 + tid;
    if (i < N_NODES){ deg[i] = 0; fill[i] = 0; }
  } else if (b < 324){                            // wswz W1 (F=128, KT=4): 32768 elems
    int t = (b - 196) * 256 + tid;
    int j = t & 7, lane = (t >> 3) & 63, kt = (t >> 9) & 3, nt = t >> 11;
    int k = kt * 32 + (lane >> 4) * 8 + j;
    int n = nt * 16 + (lane & 15);
    Wb1[t] = bf ? ((const unsigned short*)S.W1)[k * 256 + n]
                : f2bf(((const float*)S.W1)[k * 256 + n]);
  } else if (b < 388){                            // wswz W2 (F=64, KT=2): 16384 elems
    int t = (b - 324) * 256 + tid;
    int j = t & 7, lane = (t >> 3) & 63, kt = (t >> 9) & 1, nt = t >> 10;
    int k = kt * 32 + (lane >> 4) * 8 + j;
    int n = nt * 16 + (lane & 15);
    Wb2[t] = bf ? ((const unsigned short*)S.W2)[k * 256 + n]
                : f2bf(((const float*)S.W2)[k * 256 + n]);
  } else if (b < 396){                            // Bsd1 fragments: 2048 elems (kt<4)
    int t = (b - 388) * 256 + tid;
    int j = t & 7, lane = (t >> 3) & 63, kt = t >> 9;
    int k = kt * 32 + (lane >> 4) * 8 + j;
    int c = lane & 15;
    float v = 0.f;
    if (c < 4){
      for (int dd = 0; dd < 4; ++dd)
        v += ldf(S.A1, k * 16 + c * 4 + dd, bf) * ldf(S.aS1, c * 4 + dd, bf);
    } else if (c < 8){
      int h = c - 4;
      for (int dd = 0; dd < 4; ++dd)
        v += ldf(S.A1, k * 16 + h * 4 + dd, bf) * ldf(S.aD1, h * 4 + dd, bf);
    }
    Bsd1f[t] = f2bf(v);
  } else if (b < 400){                            // Bsd2 fragments: 1024 elems (kt<2)
    int t = (b - 396) * 256 + tid;
    int j = t & 7, lane = (t >> 3) & 63, kt = t >> 9;
    int k = kt * 32 + (lane >> 4) * 8 + j;
    int c = lane & 15;
    float v = 0.f;
    if (c < 4){
      for (int dd = 0; dd < 4; ++dd)
        v += ldf(S.A2, k * 16 + c * 4 + dd, bf) * ldf(S.aS2, c * 4 + dd, bf);
    } else if (c < 8){
      int h = c - 4;
      for (int dd = 0; dd < 4; ++dd)
        v += ldf(S.A2, k * 16 + h * 4 + dd, bf) * ldf(S.aD2, h * 4 + dd, bf);
    }
    Bsd2f[t] = f2bf(v);
  } else {                                        // bias copies
    if (tid < 64)       bc1[tid] = ldf(S.b1, tid, bf);
    else if (tid < 128) bc2[tid - 64] = ldf(S.b2, tid - 64, bf);
  }
}

// ---------------- CSR build (r10 form: atomic fill, no aliasing) ----------------

__global__ __launch_bounds__(256) void k_hist(const int* __restrict__ dst,
                                              int* __restrict__ deg){
  int e = blockIdx.x * 256 + threadIdx.x;
  if (e < N_EDGES) atomicAdd(&deg[dst[e]], 1);
}

__global__ __launch_bounds__(256) void k_scan1(const int* __restrict__ deg,
                                               int* __restrict__ blocksum){
  int b = blockIdx.x, t = threadIdx.x, i = b * 256 + t;
  int v = (i < N_NODES) ? deg[i] : 0;
  for (int off = 1; off < 64; off <<= 1) v += __shfl_xor(v, off);
  __shared__ int sm[4];
  if ((t & 63) == 0) sm[t >> 6] = v;
  __syncthreads();
  if (t == 0) blocksum[b] = sm[0] + sm[1] + sm[2] + sm[3];
}

// fused scan2+scan3: each block locally scans the 196 blocksums, then its chunk
__global__ __launch_bounds__(256) void k_scan23(const int* __restrict__ deg,
                                                const int* __restrict__ blocksum,
                                                int* __restrict__ rowptr){
  __shared__ int sb[256];
  __shared__ int sm[256];
  int b = blockIdx.x, t = threadIdx.x, i = b * 256 + t;
  int vb = (t < NB_SCAN) ? blocksum[t] : 0;
  sb[t] = vb;
  int v = (i < N_NODES) ? deg[i] : 0;
  sm[t] = v;
  __syncthreads();
  for (int off = 1; off < 256; off <<= 1){
    int ub = (t >= off) ? sb[t - off] : 0;
    int um = (t >= off) ? sm[t - off] : 0;
    __syncthreads();
    sb[t] += ub; sm[t] += um;
    __syncthreads();
  }
  int blockoff = (b > 0) ? sb[b - 1] : 0;         // exclusive prefix of blocksums
  if (i < N_NODES) rowptr[i] = blockoff + sm[t] - v;
  if (i == 0) rowptr[N_NODES] = N_EDGES;
}

__global__ __launch_bounds__(256) void k_scatter(const int* __restrict__ src,
                                                 const int* __restrict__ dst,
                                                 const int* __restrict__ rowptr,
                                                 int* __restrict__ fill,
                                                 int* __restrict__ csr_src){
  int e = blockIdx.x * 256 + threadIdx.x;
  if (e < N_EDGES){
    int d = dst[e];
    int pos = rowptr[d] + atomicAdd(&fill[d], 1);
    csr_src[pos] = src[e];
  }
}

// ---------------- node transform via MFMA (F = 128 or 64) ----------------
// block = 256 = 4 waves, 16 nodes/wave. h = x@W via mfma_f32_16x16x32_bf16,
// fp16 store. Alphas via KT extra MFMAs vs Bsd fragments (reusing afrag):
// D_a[M][c] -> c<4: alpha_s[node,h=c], c in 4..8: alpha_d[node,h=c-4].

template<int F, bool DYN>
__global__ __launch_bounds__(256) void k_nodeM(const void* __restrict__ xin_,
    const unsigned short* __restrict__ Wb, const unsigned short* __restrict__ Bsdf,
    _Float16* __restrict__ hmat, float* __restrict__ alpha_s, float* __restrict__ alpha_d,
    const int* __restrict__ flag)
{
  const int STR = F + 8;                   // row stride in ushorts (16B pad)
  const int KT  = F / 32;                  // K-tiles of 32
  const int CH  = F / 8;                   // ushort8 chunks per row
  __shared__ unsigned short xs[64 * (F + 8)];
  const int tid = threadIdx.x;
  const int base = blockIdx.x * 64;
  bool bf = true;
  if (DYN) bf = (*flag != 0);
  for (int v = tid; v < 64 * CH; v += 256){
    int row = v / CH, c8 = v % CH;
    int node = base + row; if (node >= N_NODES) node = N_NODES - 1;
    size_t g = (size_t)node * F + c8 * 8;
    ushort8 u;
    if (!DYN || bf){
      u = *(const ushort8*)((const unsigned short*)xin_ + g);
    } else {
      const float* xf = (const float*)xin_ + g;
      float4 f0 = *(const float4*)xf, f1 = *(const float4*)(xf + 4);
      u[0]=f2bf(f0.x); u[1]=f2bf(f0.y); u[2]=f2bf(f0.z); u[3]=f2bf(f0.w);
      u[4]=f2bf(f1.x); u[5]=f2bf(f1.y); u[6]=f2bf(f1.z); u[7]=f2bf(f1.w);
    }
    *(ushort8*)&xs[row * STR + c8 * 8] = u;
  }
  __syncthreads();

  const int wave = tid >> 6, l = tid & 63;
  const int quad = l >> 4, m = l & 15;
  const int wbase = base + wave * 16;

  short8 afrag[KT];
  #pragma unroll
  for (int kt = 0; kt < KT; ++kt)
    afrag[kt] = *(const short8*)&xs[(wave * 16 + m) * STR + kt * 32 + quad * 8];

  // alphas first (small): aacc[M][c] = sum_k x[M][k] * Bsd[k][c]
  f32x4 aacc = (f32x4)0.f;
  #pragma unroll
  for (int kt = 0; kt < KT; ++kt){
    short8 sdfrag = *(const short8*)(Bsdf + ((size_t)kt * 64 + l) * 8);
    aacc = __builtin_amdgcn_mfma_f32_16x16x32_bf16(afrag[kt], sdfrag, aacc, 0, 0, 0);
  }
  if (m < 8){
    float* dstp = (m < 4) ? alpha_s : alpha_d;
    int hh = m & 3;
    #pragma unroll
    for (int r = 0; r < 4; ++r){
      int node = wbase + quad * 4 + r;
      if (node < N_NODES) dstp[node * 4 + hh] = aacc[r];
    }
  }

  f32x4 acc[16];
  #pragma unroll
  for (int nt = 0; nt < 16; ++nt) acc[nt] = (f32x4)0.f;

  #pragma unroll
  for (int nt = 0; nt < 16; ++nt){
    #pragma unroll
    for (int kt = 0; kt < KT; ++kt){
      short8 bfrag = *(const short8*)(Wb + ((size_t)(nt * KT + kt) * 64 + l) * 8);
      acc[nt] = __builtin_amdgcn_mfma_f32_16x16x32_bf16(afrag[kt], bfrag, acc[nt], 0, 0, 0);
    }
  }
  // C/D: col = nt*16 + m, node = wbase + quad*4 + r
  #pragma unroll
  for (int r = 0; r < 4; ++r){
    int node = wbase + quad * 4 + r;
    if (node < N_NODES){
      #pragma unroll
      for (int nt = 0; nt < 16; ++nt)
        hmat[(size_t)node * 256 + nt * 16 + m] = (_Float16)acc[nt][r];
    }
  }
}

// ---------------- aggregation (exact r10 version) ----------------
// block = 256 = 4 waves, one wave per dst node. Lane l: head hh=l>>4, 4 channels.
// MODE 0: write x2 bf16 (internal). MODE 1: final output (flag: bf16 else fp32).

template<int MODE>
__global__ __launch_bounds__(256) void k_aggr(
    const _Float16* __restrict__ hmat, const float* __restrict__ alpha_s,
    const float* __restrict__ alpha_d, const int* __restrict__ rowptr,
    const int* __restrict__ csr_src, const float* __restrict__ bias,
    void* __restrict__ out, const int* __restrict__ flag)
{
  const int tid = threadIdx.x;
  const int wave = tid >> 6, l = tid & 63;
  const int n = blockIdx.x * 4 + wave;
  const int hh = l >> 4;
  const float adv = alpha_d[n * 4 + hh];
  const int p0 = rowptr[n], p1 = rowptr[n + 1];
  const char* hb = (const char*)hmat + l * 8;          // lane base, 8B per half4
  const char* ab = (const char*)alpha_s + hh * 4;      // head base, 16B per node
  float4 acc = make_float4(0.f,0.f,0.f,0.f);
  float den = 0.f;
  int p = p0;
  int pa = (p0 + 3) & ~3; if (pa > p1) pa = p1;
  for (; p < pa; ++p){                                 // head to 16B alignment
    int s = csr_src[p];
    float e = *(const float*)(ab + ((unsigned)s << 4)) + adv;
    e = fmaxf(e, 0.2f * e);
    float ex = __expf(e);
    half4 hv = *(const half4*)(hb + ((unsigned)s << 9));
    den += ex;
    acc.x += ex * (float)hv.x; acc.y += ex * (float)hv.y;
    acc.z += ex * (float)hv.z; acc.w += ex * (float)hv.w;
  }
  for (; p + 4 <= p1; p += 4){
    int4 s4 = *(const int4*)(csr_src + p);             // aligned 16B
    float a0 = *(const float*)(ab + ((unsigned)s4.x << 4));
    float a1 = *(const float*)(ab + ((unsigned)s4.y << 4));
    float a2 = *(const float*)(ab + ((unsigned)s4.z << 4));
    float a3 = *(const float*)(ab + ((unsigned)s4.w << 4));
    half4 h0 = *(const half4*)(hb + ((unsigned)s4.x << 9));
    half4 h1 = *(const half4*)(hb + ((unsigned)s4.y << 9));
    half4 h2 = *(const half4*)(hb + ((unsigned)s4.z << 9));
    half4 h3 = *(const half4*)(hb + ((unsigned)s4.w << 9));
    float e0 = a0 + adv; e0 = fmaxf(e0, 0.2f * e0);
    float e1 = a1 + adv; e1 = fmaxf(e1, 0.2f * e1);
    float e2 = a2 + adv; e2 = fmaxf(e2, 0.2f * e2);
    float e3 = a3 + adv; e3 = fmaxf(e3, 0.2f * e3);
    float ex0 = __expf(e0), ex1 = __expf(e1), ex2 = __expf(e2), ex3 = __expf(e3);
    den += (ex0 + ex1) + (ex2 + ex3);
    acc.x += ex0 * (float)h0.x + ex1 * (float)h1.x + ex2 * (float)h2.x + ex3 * (float)h3.x;
    acc.y += ex0 * (float)h0.y + ex1 * (float)h1.y + ex2 * (float)h2.y + ex3 * (float)h3.y;
    acc.z += ex0 * (float)h0.z + ex1 * (float)h1.z + ex2 * (float)h2.z + ex3 * (float)h3.z;
    acc.w += ex0 * (float)h0.w + ex1 * (float)h1.w + ex2 * (float)h2.w + ex3 * (float)h3.w;
  }
  for (; p < p1; ++p){                                 // tail
    int s = csr_src[p];
    float e = *(const float*)(ab + ((unsigned)s << 4)) + adv;
    e = fmaxf(e, 0.2f * e);
    float ex = __expf(e);
    half4 hv = *(const half4*)(hb + ((unsigned)s << 9));
    den += ex;
    acc.x += ex * (float)hv.x; acc.y += ex * (float)hv.y;
    acc.z += ex * (float)hv.z; acc.w += ex * (float)hv.w;
  }
  float r = (den > 0.f) ? (1.f / den) : 0.f;
  acc.x *= r; acc.y *= r; acc.z *= r; acc.w *= r;
  acc.x += __shfl_xor(acc.x, 16); acc.y += __shfl_xor(acc.y, 16);
  acc.z += __shfl_xor(acc.z, 16); acc.w += __shfl_xor(acc.w, 16);
  acc.x += __shfl_xor(acc.x, 32); acc.y += __shfl_xor(acc.y, 32);
  acc.z += __shfl_xor(acc.z, 32); acc.w += __shfl_xor(acc.w, 32);
  if (l < 16){
    float vx = 0.25f * acc.x + bias[l * 4 + 0];
    float vy = 0.25f * acc.y + bias[l * 4 + 1];
    float vz = 0.25f * acc.z + bias[l * 4 + 2];
    float vw = 0.25f * acc.w + bias[l * 4 + 3];
    vx = fmaxf(vx, 0.1f * vx);                          // post-layer leaky 0.1
    vy = fmaxf(vy, 0.1f * vy);
    vz = fmaxf(vz, 0.1f * vz);
    vw = fmaxf(vw, 0.1f * vw);
    if (MODE == 0){
      ushort4 o = make_ushort4(f2bf(vx), f2bf(vy), f2bf(vz), f2bf(vw));
      *(ushort4*)((unsigned short*)out + (size_t)n * 64 + l * 4) = o;   // x2 bf16
    } else {
      if (*flag){
        ushort4 o = make_ushort4(f2bf(vx), f2bf(vy), f2bf(vz), f2bf(vw));
        *(ushort4*)((unsigned short*)out + (size_t)n * 64 + l * 4) = o;
      } else {
        *(float4*)((float*)out + (size_t)n * 64 + l * 4) = make_float4(vx, vy, vz, vw);
      }
    }
  }
}

// ---------------- launch ----------------

extern "C" void kernel_launch(void* const* d_in, const int* in_sizes, int n_in,
                              void* d_out, int out_size, void* d_ws, size_t ws_size,
                              hipStream_t stream)
{
  const void* x  = d_in[0];
  const int* ei  = (const int*)d_in[1];
  const int* src = ei;
  const int* dst = ei + N_EDGES;

  char* ws = (char*)d_ws;                      // footprint ~69.7 MB (r10 layout, no aliasing)
  _Float16* hmat = (_Float16*)(ws);            // [N,256] fp16 (25.6 MB)
  unsigned short* Wb1 = (unsigned short*)(ws + 25600000);  // [32768] bf16 swizzled W1
  unsigned short* Wb2 = (unsigned short*)(ws + 25665536);  // [16384] bf16 swizzled W2
  unsigned short* x2  = (unsigned short*)(ws + 51200000);  // [N,64] bf16 layer-1 output
  float* as_    = (float*)(ws + 64000000);     // [N,4]
  float* ad_    = (float*)(ws + 64800000);     // [N,4]
  int*   deg    = (int*)  (ws + 65600000);     // [N]
  int*   fill   = (int*)  (ws + 65800000);     // [N]
  int*   rowptr = (int*)  (ws + 66000000);     // [N+1]
  int*   csr    = (int*)  (ws + 66200064);     // [E] src sorted by dst, 16B-aligned
  int*   flag   = (int*)  (ws + 69400064);     // dtype flag (1 = bf16)
  float* bc1    = (float*)(ws + 69539520);     // [64]
  float* bc2    = (float*)(ws + 69609536);     // [64]
  int*   bsum   = (int*)  (ws + 69609792);     // [256]
  unsigned short* Bsd1f = (unsigned short*)(ws + 69611840);  // [2048] bf16 fragments
  unsigned short* Bsd2f = (unsigned short*)(ws + 69615936);  // [1024] bf16 fragments

  k_detect<<<1, 64, 0, stream>>>((const unsigned int*)x, flag);

  SetupPtrs S;
  S.W1 = d_in[2];  S.A1 = d_in[3];  S.aS1 = d_in[4];  S.aD1 = d_in[5];  S.b1 = d_in[6];
  S.W2 = d_in[7];  S.A2 = d_in[8];  S.aS2 = d_in[9];  S.aD2 = d_in[10]; S.b2 = d_in[11];
  k_setup<<<401, 256, 0, stream>>>(S, deg, fill, Wb1, Wb2,
                                   Bsd1f, Bsd2f, bc1, bc2, flag);

  k_hist   <<<(N_EDGES + 255) / 256, 256, 0, stream>>>(dst, deg);
  k_scan1  <<<NB_SCAN, 256, 0, stream>>>(deg, bsum);
  k_scan23 <<<NB_SCAN, 256, 0, stream>>>(deg, bsum, rowptr);
  k_scatter<<<(N_EDGES + 255) / 256, 256, 0, stream>>>(src, dst, rowptr, fill, csr);

  // layer 1 (Fin=128, dtype per flag)
  k_nodeM<128, true><<<(N_NODES + 63) / 64, 256, 0, stream>>>(x, Wb1, Bsd1f, hmat, as_, ad_, flag);
  k_aggr<0><<<N_NODES / 4, 256, 0, stream>>>(hmat, as_, ad_, rowptr, csr, bc1, x2, flag);
  // layer 2 (Fin=64, bf16 internal)
  k_nodeM<64, false><<<(N_NODES + 63) / 64, 256, 0, stream>>>(x2, Wb2, Bsd2f, hmat, as_, ad_, flag);
  k_aggr<1><<<N_NODES / 4, 256, 0, stream>>>(hmat, as_, ad_, rowptr, csr, bc2, d_out, flag);
}